// Round 11
// baseline (6857.287 us; speedup 1.0000x reference)
//
#include <hip/hip_runtime.h>
#include <math.h>

#define B 128
#define T 128
#define H 128
#define RH 4
#define M 64
#define W 128
#define VOCAB 512
#define IFACE 919
#define G4 512
#define DELTA 1e-6f
#define CLIPV 20.0f

#define MEMLD 132   // mem row stride (W=128 + 4)
#define LNKLD 67    // link row stride (M=64 + 3)

__device__ __forceinline__ float sigmoidf_(float x){ return 1.0f/(1.0f+expf(-x)); }
__device__ __forceinline__ float softplusf_(float x){
  return fmaxf(x, 0.0f) + log1pf(expf(-fabsf(x)));
}
__device__ __forceinline__ float waveAllSum(float v){
  for (int off=1; off<64; off<<=1) v += __shfl_xor(v, off, 64);
  return v;
}
__device__ __forceinline__ float waveAllMax(float v){
  for (int off=1; off<64; off<<=1) v = fmaxf(v, __shfl_xor(v, off, 64));
  return v;
}

__global__ void k_transpose(const float* __restrict__ in, float* __restrict__ out,
                            int rows, int cols, int use_cols){
  int idx = blockIdx.x*blockDim.x + threadIdx.x;
  int total = rows*use_cols;
  if (idx < total){
    int r = idx / use_cols, c = idx - r*use_cols;
    out[c*rows + r] = in[r*cols + c];
  }
}

// xw0[v][g] = emb[v]·w_ih0[g][0:128] + b_ih0[g] + b_hh0[g]  (coalesced via wih0T)
__global__ void k_xw0(const float* __restrict__ emb, const float* __restrict__ wih0T,
                      const float* __restrict__ b_ih0, const float* __restrict__ b_hh0,
                      float* __restrict__ xw0){
  __shared__ float e[H];
  int v = blockIdx.x, g = threadIdx.x;
  if (g < H) e[g] = emb[v*H + g];
  __syncthreads();
  float acc = b_ih0[g] + b_hh0[g];
  #pragma unroll 8
  for (int k=0;k<H;k++) acc += e[k]*wih0T[k*G4 + g];
  xw0[v*G4 + g] = acc;
}

// fused tail: per 32 (b,t) rows -> Y = stash·w_out^T + b_out -> logits -> out
__launch_bounds__(512, 1)
__global__ void k_tail(const float* __restrict__ stash, const float* __restrict__ w_out,
                       const float* __restrict__ b_out, const float* __restrict__ w_fc,
                       const float* __restrict__ b_fc, float* __restrict__ out){
  __shared__ __align__(16) float S[32*644];
  __shared__ float Y[32*129];
  const int tid = threadIdx.x;
  const long bt0 = (long)blockIdx.x*32;

  for (int idx = tid; idx < 32*640; idx += 512){
    int bt = idx / 640, k = idx - bt*640;
    S[bt*644 + k] = stash[(bt0+bt)*640 + k];
  }
  __syncthreads();
  { // Y[bt][o]
    int og = tid >> 5, bt = tid & 31;
    const float4* s4 = (const float4*)(S + bt*644);
    #pragma unroll
    for (int oo = 0; oo < 8; ++oo){
      int o = og*8 + oo;
      const float4* w4 = (const float4*)(w_out + (size_t)o*640);
      float acc = b_out[o];
      #pragma unroll 8
      for (int k4 = 0; k4 < 160; ++k4){
        float4 w = w4[k4], s = s4[k4];
        acc += w.x*s.x + w.y*s.y + w.z*s.z + w.w*s.w;
      }
      Y[bt*129 + o] = acc;
    }
  }
  __syncthreads();
  { // logits, coalesced on t
    int t = tid & 31, vg = tid >> 5;
    int b  = (int)(bt0 >> 7);
    int tb = (int)(bt0 & 127);
    const float* yr = Y + t*129;
    #pragma unroll 2
    for (int vv = 0; vv < 32; ++vv){
      int v = vg*32 + vv;
      const float4* w4 = (const float4*)(w_fc + (size_t)v*H);
      float acc = b_fc[v];
      #pragma unroll 8
      for (int k4 = 0; k4 < 32; ++k4){
        float4 w = w4[k4];
        int k = k4*4;
        acc += w.x*yr[k] + w.y*yr[k+1] + w.z*yr[k+2] + w.w*yr[k+3];
      }
      out[((size_t)b*VOCAB + v)*T + tb + t] = acc;
    }
  }
}

__launch_bounds__(512, 1)
__global__ void k_dnc(const int* __restrict__ tokens,
                      const float* __restrict__ xw0,
                      const float* __restrict__ whh0T,
                      const float* __restrict__ w1catT,
                      const float* __restrict__ b_ih1,
                      const float* __restrict__ b_hh1,
                      const float* __restrict__ wifaceT,
                      const float* __restrict__ b_iface,
                      const float* __restrict__ h0,
                      float* __restrict__ stash)
{
  const int b = blockIdx.x;
  const int tid = threadIdx.x;
  const int lane = tid & 63;
  const int wave = tid >> 6;

  __shared__ __align__(16) float hcat[2*H];           // h0 || h1
  __shared__ __align__(16) float c0s[H], c1s[H], outv[H];
  __shared__ __align__(16) float mem[M*MEMLD];
  __shared__ float link[M*LNKLD];
  __shared__ float prec[M], ww[M], usage[M];
  __shared__ float rw[RH*M];
  __shared__ __align__(16) float gates[G4];
  __shared__ __align__(16) float xi[920];
  __shared__ __align__(16) float rk[RH*W];
  __shared__ float wk[W], er[W], wv[W];
  __shared__ float memnorm[M];
  __shared__ float wcw[M], alloc_s[M];
  __shared__ float cwm[RH*M], fwd[RH*M], bwd[RH*M];
  __shared__ int   tok[T];
  __shared__ float rstr[RH], fg[RH], rmode[RH*3];
  __shared__ float s_wstr, s_ag, s_wg, s_wwsum, s_wkinv, s_rkinv[RH];

  // loop-invariant hoist (LSTM1 bias)
  const float b1sum = b_ih1[tid] + b_hh1[tid];

  // ====== mv0 weight column lives in REGISTERS for the whole scan ==========
  // thread tid holds whh0T[k][tid], k=0..127 (128 VGPRs; budget 80+128<256,
  // occupancy unchanged at 2 waves/SIMD). Loaded once; mv0 has zero L2 reads.
  float wreg[H];
  #pragma unroll
  for (int k=0;k<H;k++) wreg[k] = whh0T[k*G4 + tid];

  if (tid < H){
    float hv0 = h0[0*B*H + b*H + tid];
    float hv1 = h0[1*B*H + b*H + tid];
    hcat[tid]=hv0; hcat[H+tid]=hv1; c0s[tid]=hv0; c1s[tid]=hv1;
  }
  if (tid < T) tok[tid] = tokens[b*T + tid];
  for (int i = tid; i < M*MEMLD; i += 512) mem[i]=0.f;
  for (int i = tid; i < M*LNKLD; i += 512) link[i]=0.f;
  if (tid < M){ prec[tid]=0.f; ww[tid]=0.f; usage[tid]=0.f; }
  if (tid < RH*M) rw[tid]=0.f;
  __syncthreads();

  for (int t = 0; t < T; ++t){
    const long bt = (long)b*T + t;

    // ====== mv0: gates = xw0[token] + wreg·h0  (register weights, 4 chains) =
    {
      float acc = xw0[(size_t)tok[t]*G4 + tid];
      const float4* h4 = (const float4*)hcat;
      float a0=0.f,a1=0.f,a2=0.f,a3=0.f;
      #pragma unroll
      for (int i=0;i<32;i++){
        float4 h = h4[i];
        a0 += h.x*wreg[4*i  ];
        a1 += h.y*wreg[4*i+1];
        a2 += h.z*wreg[4*i+2];
        a3 += h.w*wreg[4*i+3];
      }
      gates[tid] = acc + ((a0+a1)+(a2+a3));
    }
    __syncthreads();
    // ---- pw0
    if (tid < H){
      float ig = sigmoidf_(gates[tid]);
      float ff = sigmoidf_(gates[H+tid]);
      float gg = tanhf(gates[2*H+tid]);
      float og = sigmoidf_(gates[3*H+tid]);
      float c2 = ff*c0s[tid] + ig*gg;
      c0s[tid] = c2;
      hcat[tid] = og*tanhf(c2);
    }
    __syncthreads();

    // ====== mv1: R7 verbatim + hidden pre-write mem-norm scan ===============
    {
      float acc = b1sum;
      const float* wp1 = w1catT + tid;            // k in [0,128)   -> w_ih1
      const float* wp2 = w1catT + 128*G4 + tid;   // k in [128,256) -> w_hh1
      #pragma unroll 4
      for (int k=0;k<H;k++) acc += hcat[k]*wp1[k*G4] + hcat[H+k]*wp2[k*G4];
      gates[tid] = acc;

      int row = tid >> 3, sub = tid & 7;
      float ss = 0.f;
      #pragma unroll
      for (int i=0;i<16;i++){ float v = mem[row*MEMLD + sub + 8*i]; ss += v*v; }
      ss += __shfl_down(ss,4,8); ss += __shfl_down(ss,2,8); ss += __shfl_down(ss,1,8);
      if (sub==0) memnorm[row] = 1.0f/(sqrtf(ss)+DELTA);
    }
    __syncthreads();
    // ---- pw1 (+ stash first 128)
    if (tid < H){
      float ig = sigmoidf_(gates[tid]);
      float ff = sigmoidf_(gates[H+tid]);
      float gg = tanhf(gates[2*H+tid]);
      float og = sigmoidf_(gates[3*H+tid]);
      float c2 = ff*c1s[tid] + ig*gg;
      c1s[tid] = c2;
      float h2 = og*tanhf(c2);
      hcat[H+tid] = h2;
      float ov = fminf(fmaxf(h2, -CLIPV), CLIPV);
      outv[tid] = ov;
      stash[bt*640 + tid] = ov;
    }
    __syncthreads();

    // ====== iface: xi = w_iface^T·outv + b_iface  (R7 verbatim) =============
    for (int j = tid; j < IFACE; j += 512){
      float acc = b_iface[j];
      const float* wp = wifaceT + j;
      #pragma unroll 8
      for (int k=0;k<H;k++) acc += outv[k]*wp[k*IFACE];
      xi[j] = acc;
    }
    __syncthreads();

    // ====== parse + usage update + key norms (merged, R10 verbatim) =========
    rk[tid] = tanhf(xi[tid]);
    if (tid < W){
      wk[tid] = tanhf(xi[516+tid]);
      er[tid] = sigmoidf_(xi[645+tid]);
      wv[tid] = tanhf(xi[773+tid]);
    }
    if (tid < RH){
      rstr[tid] = softplusf_(xi[512+tid]);
      fg[tid]   = sigmoidf_(xi[901+tid]);
      float a0 = xi[907+3*tid], a1 = xi[908+3*tid], a2 = xi[909+3*tid];
      float mx = fmaxf(a0, fmaxf(a1,a2));
      float e0=expf(a0-mx), e1=expf(a1-mx), e2=expf(a2-mx);
      float s = e0+e1+e2;
      rmode[3*tid]=e0/s; rmode[3*tid+1]=e1/s; rmode[3*tid+2]=e2/s;
    }
    if (tid == 0){
      s_wstr = softplusf_(xi[644]);
      s_ag = sigmoidf_(xi[905]);
      s_wg = sigmoidf_(xi[906]);
    }
    if (tid < M){   // usage update (prev ww, prev rw); fg recomputed from xi
      float f0 = sigmoidf_(xi[901]);
      float f1 = sigmoidf_(xi[902]);
      float f2 = sigmoidf_(xi[903]);
      float f3 = sigmoidf_(xi[904]);
      float um = usage[tid] + (1.0f-usage[tid])*ww[tid];
      float psi = (1.0f - f0*rw[tid])      * (1.0f - f1*rw[M+tid])
                * (1.0f - f2*rw[2*M+tid])  * (1.0f - f3*rw[3*M+tid]);
      usage[tid] = um*psi;
    }
    if (wave == 0){      // write-key norm (tanh recomputed from xi)
      float v0 = tanhf(xi[516+lane]), v1 = tanhf(xi[516+lane+64]);
      float ss = waveAllSum(v0*v0+v1*v1);
      if (lane==0) s_wkinv = 1.0f/(sqrtf(ss)+DELTA);
    } else if (wave <= RH){   // read-key norms
      int r = wave-1;
      float v0 = tanhf(xi[r*W+lane]), v1 = tanhf(xi[r*W+lane+64]);
      float ss = waveAllSum(v0*v0+v1*v1);
      if (lane==0) s_rkinv[r] = 1.0f/(sqrtf(ss)+DELTA);
    }
    __syncthreads();

    // ---- Phase C: write content scores (pre-write memory)
    {
      int m = tid >> 3, sub = tid & 7;
      float d = 0.f;
      #pragma unroll
      for (int i=0;i<16;i++){ int e = sub + 8*i; d += mem[m*MEMLD + e]*wk[e]; }
      d += __shfl_down(d,4,8); d += __shfl_down(d,2,8); d += __shfl_down(d,1,8);
      if (sub==0) wcw[m] = d * memnorm[m] * s_wkinv * s_wstr;
    }
    __syncthreads();

    // ---- Phase D: wave0 softmax(wcw); wave1 allocation via bitonic argsort
    if (wave == 0){
      float x = wcw[lane];
      float mx = waveAllMax(x);
      float e = expf(x-mx);
      float s = waveAllSum(e);
      wcw[lane] = e/s;
    } else if (wave == 1){
      float u = DELTA + (1.0f-DELTA)*usage[lane];
      int idx = lane;
      for (int k=2;k<=64;k<<=1){
        for (int j=k>>1;j>0;j>>=1){
          float ou = __shfl_xor(u, j, 64);
          int   oi = __shfl_xor(idx, j, 64);
          bool up = ((lane & k) == 0);
          bool iLower = ((lane & j) == 0);
          bool otherLess = (ou < u) || (ou == u && oi < idx);
          bool takeOther = (up == iLower) ? otherLess : !otherLess;
          if (takeOther){ u = ou; idx = oi; }
        }
      }
      float p = u;
      for (int d=1; d<64; d<<=1){
        float pv = __shfl_up(p, d, 64);
        if (lane >= d) p *= pv;
      }
      float ep = __shfl_up(p, 1, 64);
      if (lane == 0) ep = 1.0f;
      alloc_s[idx] = (1.0f - u) * ep;
    }
    __syncthreads();

    // ---- Phase E: write weights + sum
    if (tid < M){
      float wwm = s_wg*(s_ag*alloc_s[tid] + (1.0f-s_ag)*wcw[tid]);
      ww[tid] = wwm;
      float s = waveAllSum(wwm);
      if (lane==0) s_wwsum = s;
    }
    __syncthreads();

    // ---- Phase F: memory write + link update (old prec)
    #pragma unroll
    for (int e=0;e<16;e++){
      int f = tid + 512*e;
      int m = f >> 7, w = f & 127;
      mem[m*MEMLD+w] = mem[m*MEMLD+w]*(1.0f - ww[m]*er[w]) + ww[m]*wv[w];
    }
    #pragma unroll
    for (int e=0;e<8;e++){
      int f = tid + 512*e;
      int i = f >> 6, j = f & 63;
      float lv = (1.0f - ww[i] - ww[j])*link[i*LNKLD+j] + ww[i]*prec[j];
      link[i*LNKLD+j] = (i==j) ? 0.0f : lv;
    }
    __syncthreads();

    // ---- Phase G: precedence update + post-write mem norms
    if (tid < M) prec[tid] = (1.0f - s_wwsum)*prec[tid] + ww[tid];
    {
      int row = tid >> 3, sub = tid & 7;
      float ss = 0.f;
      #pragma unroll
      for (int i=0;i<16;i++){ float v = mem[row*MEMLD + sub + 8*i]; ss += v*v; }
      ss += __shfl_down(ss,4,8); ss += __shfl_down(ss,2,8); ss += __shfl_down(ss,1,8);
      if (sub==0) memnorm[row] = 1.0f/(sqrtf(ss)+DELTA);
    }
    __syncthreads();

    // ---- Phase H+J (merged): read dots AND fwd/bwd via link (old rw)
    {
      int r = tid >> 7, m = (tid >> 1) & 63, sub = tid & 1;
      float d = 0.f;
      #pragma unroll 8
      for (int i=0;i<64;i++){ int e = sub + 2*i; d += mem[m*MEMLD + e]*rk[r*W + e]; }
      d += __shfl_down(d,1,2);
      if (sub==0) cwm[r*M+m] = d * memnorm[m] * s_rkinv[r] * rstr[r];
    }
    if (tid < 256){
      int r = tid >> 6, i = tid & 63;
      float a = 0.f;
      #pragma unroll 8
      for (int j=0;j<M;j++) a += link[i*LNKLD+j]*rw[r*M+j];
      fwd[r*M+i] = a;
    } else {
      int q = tid - 256;
      int r = q >> 6, j = q & 63;
      float a = 0.f;
      #pragma unroll 8
      for (int i=0;i<M;i++) a += rw[r*M+i]*link[i*LNKLD+j];
      bwd[r*M+j] = a;
    }
    __syncthreads();

    // ---- Phase I+K (merged): per-head softmax, rw updated in-register
    if (wave < RH){
      int r = wave;
      float x = cwm[r*M + lane];
      float mx = waveAllMax(x);
      float e = expf(x-mx);
      float s = waveAllSum(e);
      float c = e/s;
      rw[r*M+lane] = rmode[3*r]*bwd[r*M+lane] + rmode[3*r+1]*fwd[r*M+lane]
                   + rmode[3*r+2]*c;
    }
    __syncthreads();

    // ---- Phase L: read vectors -> stash
    {
      int r = tid >> 7, w = tid & 127;
      float a = 0.f;
      #pragma unroll 8
      for (int m=0;m<M;m++) a += rw[r*M+m]*mem[m*MEMLD+w];
      stash[bt*640 + 128 + tid] = a;
    }
  }
}

extern "C" void kernel_launch(void* const* d_in, const int* in_sizes, int n_in,
                              void* d_out, int out_size, void* d_ws, size_t ws_size,
                              hipStream_t stream)
{
  const int*   tokens  = (const int*)d_in[0];
  const float* emb     = (const float*)d_in[1];
  const float* w_ih0   = (const float*)d_in[2];
  const float* w_hh0   = (const float*)d_in[3];
  const float* b_ih0   = (const float*)d_in[4];
  const float* b_hh0   = (const float*)d_in[5];
  const float* w_ih1   = (const float*)d_in[6];
  const float* w_hh1   = (const float*)d_in[7];
  const float* b_ih1   = (const float*)d_in[8];
  const float* b_hh1   = (const float*)d_in[9];
  const float* w_iface = (const float*)d_in[10];
  const float* b_iface = (const float*)d_in[11];
  const float* w_out   = (const float*)d_in[12];
  const float* b_out   = (const float*)d_in[13];
  const float* w_fc    = (const float*)d_in[14];
  const float* b_fc    = (const float*)d_in[15];
  const float* h0      = (const float*)d_in[16];
  float* out = (float*)d_out;
  float* ws  = (float*)d_ws;

  float* xw0     = ws;                   // 512*512    = 262144
  float* whh0T   = xw0     + 262144;     // 128*512    = 65536
  float* w1catT  = whh0T   + 65536;      // 256*512    = 131072
  float* wifaceT = w1catT  + 131072;     // 128*919    = 117632
  float* wih0T   = wifaceT + 117632;     // 128*512    = 65536 (temp for xw0)
  float* stash   = wih0T   + 65536;      // 16384*640  = 10485760
  // total ~11.1M floats = 44.5 MB

  auto tp = [&](const float* in, float* o, int rows, int cols, int use){
    int total = rows*use;
    k_transpose<<<(total+255)/256, 256, 0, stream>>>(in, o, rows, cols, use);
  };
  tp(w_ih0,   wih0T,          512, 640, 128);
  tp(w_hh0,   whh0T,          512, 128, 128);
  tp(w_ih1,   w1catT,         512, 128, 128);
  tp(w_hh1,   w1catT+128*G4,  512, 128, 128);
  tp(w_iface, wifaceT,        919, 128, 128);
  k_xw0<<<VOCAB, 512, 0, stream>>>(emb, wih0T, b_ih0, b_hh0, xw0);
  k_dnc<<<B, 512, 0, stream>>>(tokens, xw0, whh0T, w1catT, b_ih1, b_hh1,
                               wifaceT, b_iface, h0, stash);
  k_tail<<<(B*T)/32, 512, 0, stream>>>(stash, w_out, b_out, w_fc, b_fc, out);
}

// Round 12
// 5859.869 us; speedup vs baseline: 1.1702x; 1.1702x over previous
//
#include <hip/hip_runtime.h>
#include <math.h>

#define B 128
#define T 128
#define H 128
#define RH 4
#define M 64
#define W 128
#define VOCAB 512
#define IFACE 919
#define G4 512
#define DELTA 1e-6f
#define CLIPV 20.0f

#define MEMLD 132   // mem row stride (W=128 + 4)
#define LNKLD 67    // link row stride (M=64 + 3)

__device__ __forceinline__ float sigmoidf_(float x){ return 1.0f/(1.0f+expf(-x)); }
__device__ __forceinline__ float softplusf_(float x){
  return fmaxf(x, 0.0f) + log1pf(expf(-fabsf(x)));
}
__device__ __forceinline__ float waveAllSum(float v){
  for (int off=1; off<64; off<<=1) v += __shfl_xor(v, off, 64);
  return v;
}
__device__ __forceinline__ float waveAllMax(float v){
  for (int off=1; off<64; off<<=1) v = fmaxf(v, __shfl_xor(v, off, 64));
  return v;
}

// pairwise block handshake: publish my flag=want, wait partner's >= want.
// agent-scope release/acquire orders the data buffers (cross-XCD safe).
__device__ __forceinline__ void xsync(unsigned* myf, unsigned* pf, unsigned want,
                                      int tid){
  __syncthreads();                       // all data stores issued (vmcnt drained)
  if (tid == 0){
    __hip_atomic_store(myf, want, __ATOMIC_RELEASE, __HIP_MEMORY_SCOPE_AGENT);
    while (__hip_atomic_load(pf, __ATOMIC_ACQUIRE, __HIP_MEMORY_SCOPE_AGENT) < want)
      __builtin_amdgcn_s_sleep(1);
  }
  __syncthreads();
}

__global__ void k_transpose(const float* __restrict__ in, float* __restrict__ out,
                            int rows, int cols, int use_cols){
  int idx = blockIdx.x*blockDim.x + threadIdx.x;
  int total = rows*use_cols;
  if (idx < total){
    int r = idx / use_cols, c = idx - r*use_cols;
    out[c*rows + r] = in[r*cols + c];
  }
}

// xw0[v][g] = emb[v]·w_ih0[g][0:128] + b_ih0[g] + b_hh0[g]  (coalesced via wih0T)
__global__ void k_xw0(const float* __restrict__ emb, const float* __restrict__ wih0T,
                      const float* __restrict__ b_ih0, const float* __restrict__ b_hh0,
                      float* __restrict__ xw0){
  __shared__ float e[H];
  int v = blockIdx.x, g = threadIdx.x;
  if (g < H) e[g] = emb[v*H + g];
  __syncthreads();
  float acc = b_ih0[g] + b_hh0[g];
  #pragma unroll 8
  for (int k=0;k<H;k++) acc += e[k]*wih0T[k*G4 + g];
  xw0[v*G4 + g] = acc;
}

// fused tail: per 32 (b,t) rows -> Y = stash·w_out^T + b_out -> logits -> out
__launch_bounds__(512, 1)
__global__ void k_tail(const float* __restrict__ stash, const float* __restrict__ w_out,
                       const float* __restrict__ b_out, const float* __restrict__ w_fc,
                       const float* __restrict__ b_fc, float* __restrict__ out){
  __shared__ __align__(16) float S[32*644];
  __shared__ float Y[32*129];
  const int tid = threadIdx.x;
  const long bt0 = (long)blockIdx.x*32;

  for (int idx = tid; idx < 32*640; idx += 512){
    int bt = idx / 640, k = idx - bt*640;
    S[bt*644 + k] = stash[(bt0+bt)*640 + k];
  }
  __syncthreads();
  { // Y[bt][o]
    int og = tid >> 5, bt = tid & 31;
    const float4* s4 = (const float4*)(S + bt*644);
    #pragma unroll
    for (int oo = 0; oo < 8; ++oo){
      int o = og*8 + oo;
      const float4* w4 = (const float4*)(w_out + (size_t)o*640);
      float acc = b_out[o];
      #pragma unroll 8
      for (int k4 = 0; k4 < 160; ++k4){
        float4 w = w4[k4], s = s4[k4];
        acc += w.x*s.x + w.y*s.y + w.z*s.z + w.w*s.w;
      }
      Y[bt*129 + o] = acc;
    }
  }
  __syncthreads();
  { // logits, coalesced on t
    int t = tid & 31, vg = tid >> 5;
    int b  = (int)(bt0 >> 7);
    int tb = (int)(bt0 & 127);
    const float* yr = Y + t*129;
    #pragma unroll 2
    for (int vv = 0; vv < 32; ++vv){
      int v = vg*32 + vv;
      const float4* w4 = (const float4*)(w_fc + (size_t)v*H);
      float acc = b_fc[v];
      #pragma unroll 8
      for (int k4 = 0; k4 < 32; ++k4){
        float4 w = w4[k4];
        int k = k4*4;
        acc += w.x*yr[k] + w.y*yr[k+1] + w.z*yr[k+2] + w.w*yr[k+3];
      }
      out[((size_t)b*VOCAB + v)*T + tb + t] = acc;
    }
  }
}

// pair-split DNC: blockIdx = 2*b + half. Each half computes half of each weight
// matvec's outputs (R7-proven per-thread pattern); halves exchange via global
// buffers + flag handshakes. DNC LDS phases run redundantly (identical state).
__launch_bounds__(512, 1)
__global__ void k_dnc(const int* __restrict__ tokens,
                      const float* __restrict__ xw0,
                      const float* __restrict__ whh0T,
                      const float* __restrict__ w1catT,
                      const float* __restrict__ b_ih1,
                      const float* __restrict__ b_hh1,
                      const float* __restrict__ wifaceT,
                      const float* __restrict__ b_iface,
                      const float* __restrict__ h0,
                      float* __restrict__ stash,
                      float* __restrict__ xbuf,
                      unsigned* __restrict__ flags)
{
  const int pair = blockIdx.x >> 1;     // batch element
  const int half = blockIdx.x & 1;
  const int b = pair;
  const int tid = threadIdx.x;
  const int lane = tid & 63;
  const int wave = tid >> 6;

  float* gxa = xbuf + pair*512;                 // gates exchange (mv0)
  float* gxb = xbuf + 65536  + pair*512;        // gates exchange (mv1)
  float* gxc = xbuf + 131072 + (size_t)pair*928;// xi exchange
  unsigned* myf = flags + pair*6 + half*3;
  unsigned* pf  = flags + pair*6 + (1-half)*3;

  __shared__ __align__(16) float hcat[2*H];           // h0 || h1
  __shared__ __align__(16) float c0s[H], c1s[H], outv[H];
  __shared__ __align__(16) float mem[M*MEMLD];
  __shared__ float link[M*LNKLD];
  __shared__ float prec[M], ww[M], usage[M];
  __shared__ float rw[RH*M];
  __shared__ __align__(16) float rk[RH*W];
  __shared__ float wk[W], er[W], wv[W];
  __shared__ float memnorm[M];
  __shared__ float wcw[M], alloc_s[M];
  __shared__ float cwm[RH*M], fwd[RH*M], bwd[RH*M];
  __shared__ int   tok[T];
  __shared__ float rstr[RH], fg[RH], rmode[RH*3];
  __shared__ float s_wstr, s_ag, s_wg, s_wwsum, s_wkinv, s_rkinv[RH];

  // per-half output indices + hoisted biases
  const int o01 = half*256 + tid;                       // mv0/mv1 output (tid<256)
  const float b1sum = (tid < 256) ? (b_ih1[o01] + b_hh1[o01]) : 0.f;
  const int nif = half ? 459 : 460;                     // iface outputs this half
  const int oif = half ? (460 + tid) : tid;             // iface output (tid<nif)
  const float bif = (tid < nif) ? b_iface[oif] : 0.f;

  if (tid < H){
    float hv0 = h0[0*B*H + b*H + tid];
    float hv1 = h0[1*B*H + b*H + tid];
    hcat[tid]=hv0; hcat[H+tid]=hv1; c0s[tid]=hv0; c1s[tid]=hv1;
  }
  if (tid < T) tok[tid] = tokens[b*T + tid];
  for (int i = tid; i < M*MEMLD; i += 512) mem[i]=0.f;
  for (int i = tid; i < M*LNKLD; i += 512) link[i]=0.f;
  if (tid < M){ prec[tid]=0.f; ww[tid]=0.f; usage[tid]=0.f; }
  if (tid < RH*M) rw[tid]=0.f;
  __syncthreads();

  for (int t = 0; t < T; ++t){
    const long bt = (long)b*T + t;
    const unsigned want = (unsigned)(t+1);

    // ====== mv0 half (tid<256, R7 pattern) ∥ pre-write mem-norm scan ========
    if (tid < 256){
      float acc = xw0[(size_t)tok[t]*G4 + o01];
      const float* wp = whh0T + o01;
      #pragma unroll 8
      for (int k=0;k<H;k++) acc += hcat[k]*wp[k*G4];
      gxa[o01] = acc;
    } else {
      int q = tid - 256, row = q >> 2, sub = q & 3;
      float ss = 0.f;
      #pragma unroll
      for (int i=0;i<32;i++){ float v = mem[row*MEMLD + sub + 4*i]; ss += v*v; }
      ss += __shfl_down(ss,2,4); ss += __shfl_down(ss,1,4);
      if (sub==0) memnorm[row] = 1.0f/(sqrtf(ss)+DELTA);
    }
    xsync(myf+0, pf+0, want, tid);

    // ---- pw0: read full gates straight from exchange buffer
    if (tid < H){
      float ig = sigmoidf_(gxa[tid]);
      float ff = sigmoidf_(gxa[H+tid]);
      float gg = tanhf(gxa[2*H+tid]);
      float og = sigmoidf_(gxa[3*H+tid]);
      float c2 = ff*c0s[tid] + ig*gg;
      c0s[tid] = c2;
      hcat[tid] = og*tanhf(c2);
    }
    __syncthreads();

    // ====== mv1 half (tid<256, R7 pattern, K=256) ===========================
    if (tid < 256){
      float acc = b1sum;
      const float* wp1 = w1catT + o01;            // k in [0,128)   -> w_ih1
      const float* wp2 = w1catT + 128*G4 + o01;   // k in [128,256) -> w_hh1
      #pragma unroll 4
      for (int k=0;k<H;k++) acc += hcat[k]*wp1[k*G4] + hcat[H+k]*wp2[k*G4];
      gxb[o01] = acc;
    }
    xsync(myf+1, pf+1, want, tid);

    // ---- pw1 (+ stash first 128, half 0 only)
    if (tid < H){
      float ig = sigmoidf_(gxb[tid]);
      float ff = sigmoidf_(gxb[H+tid]);
      float gg = tanhf(gxb[2*H+tid]);
      float og = sigmoidf_(gxb[3*H+tid]);
      float c2 = ff*c1s[tid] + ig*gg;
      c1s[tid] = c2;
      float h2 = og*tanhf(c2);
      hcat[H+tid] = h2;
      float ov = fminf(fmaxf(h2, -CLIPV), CLIPV);
      outv[tid] = ov;
      if (half == 0) stash[bt*640 + tid] = ov;
    }
    __syncthreads();

    // ====== iface half (R7 pattern, 1 output/thread) ========================
    if (tid < nif){
      float acc = bif;
      const float* wp = wifaceT + oif;
      #pragma unroll 8
      for (int k=0;k<H;k++) acc += outv[k]*wp[k*IFACE];
      gxc[oif] = acc;
    }
    xsync(myf+2, pf+2, want, tid);

    // ====== parse + usage update + key norms (reads xi from exchange buf) ===
    {
      const float* xig = gxc;
      rk[tid] = tanhf(xig[tid]);
      if (tid < W){
        wk[tid] = tanhf(xig[516+tid]);
        er[tid] = sigmoidf_(xig[645+tid]);
        wv[tid] = tanhf(xig[773+tid]);
      }
      if (tid < RH){
        rstr[tid] = softplusf_(xig[512+tid]);
        fg[tid]   = sigmoidf_(xig[901+tid]);
        float a0 = xig[907+3*tid], a1 = xig[908+3*tid], a2 = xig[909+3*tid];
        float mx = fmaxf(a0, fmaxf(a1,a2));
        float e0=expf(a0-mx), e1=expf(a1-mx), e2=expf(a2-mx);
        float s = e0+e1+e2;
        rmode[3*tid]=e0/s; rmode[3*tid+1]=e1/s; rmode[3*tid+2]=e2/s;
      }
      if (tid == 0){
        s_wstr = softplusf_(xig[644]);
        s_ag = sigmoidf_(xig[905]);
        s_wg = sigmoidf_(xig[906]);
      }
      if (tid < M){   // usage update (prev ww, prev rw); fg recomputed from xi
        float f0 = sigmoidf_(xig[901]);
        float f1 = sigmoidf_(xig[902]);
        float f2 = sigmoidf_(xig[903]);
        float f3 = sigmoidf_(xig[904]);
        float um = usage[tid] + (1.0f-usage[tid])*ww[tid];
        float psi = (1.0f - f0*rw[tid])      * (1.0f - f1*rw[M+tid])
                  * (1.0f - f2*rw[2*M+tid])  * (1.0f - f3*rw[3*M+tid]);
        usage[tid] = um*psi;
      }
      if (wave == 0){      // write-key norm (tanh recomputed from xi)
        float v0 = tanhf(xig[516+lane]), v1 = tanhf(xig[516+lane+64]);
        float ss = waveAllSum(v0*v0+v1*v1);
        if (lane==0) s_wkinv = 1.0f/(sqrtf(ss)+DELTA);
      } else if (wave <= RH){   // read-key norms
        int r = wave-1;
        float v0 = tanhf(xig[r*W+lane]), v1 = tanhf(xig[r*W+lane+64]);
        float ss = waveAllSum(v0*v0+v1*v1);
        if (lane==0) s_rkinv[r] = 1.0f/(sqrtf(ss)+DELTA);
      }
    }
    __syncthreads();

    // ---- Phase C: write content scores (pre-write memory)
    {
      int m = tid >> 3, sub = tid & 7;
      float d = 0.f;
      #pragma unroll
      for (int i=0;i<16;i++){ int e = sub + 8*i; d += mem[m*MEMLD + e]*wk[e]; }
      d += __shfl_down(d,4,8); d += __shfl_down(d,2,8); d += __shfl_down(d,1,8);
      if (sub==0) wcw[m] = d * memnorm[m] * s_wkinv * s_wstr;
    }
    __syncthreads();

    // ---- Phase D: wave0 softmax(wcw); wave1 allocation via bitonic argsort
    if (wave == 0){
      float x = wcw[lane];
      float mx = waveAllMax(x);
      float e = expf(x-mx);
      float s = waveAllSum(e);
      wcw[lane] = e/s;
    } else if (wave == 1){
      float u = DELTA + (1.0f-DELTA)*usage[lane];
      int idx = lane;
      for (int k=2;k<=64;k<<=1){
        for (int j=k>>1;j>0;j>>=1){
          float ou = __shfl_xor(u, j, 64);
          int   oi = __shfl_xor(idx, j, 64);
          bool up = ((lane & k) == 0);
          bool iLower = ((lane & j) == 0);
          bool otherLess = (ou < u) || (ou == u && oi < idx);
          bool takeOther = (up == iLower) ? otherLess : !otherLess;
          if (takeOther){ u = ou; idx = oi; }
        }
      }
      float p = u;
      for (int d=1; d<64; d<<=1){
        float pv = __shfl_up(p, d, 64);
        if (lane >= d) p *= pv;
      }
      float ep = __shfl_up(p, 1, 64);
      if (lane == 0) ep = 1.0f;
      alloc_s[idx] = (1.0f - u) * ep;
    }
    __syncthreads();

    // ---- Phase E: write weights + sum
    if (tid < M){
      float wwm = s_wg*(s_ag*alloc_s[tid] + (1.0f-s_ag)*wcw[tid]);
      ww[tid] = wwm;
      float s = waveAllSum(wwm);
      if (lane==0) s_wwsum = s;
    }
    __syncthreads();

    // ---- Phase F: memory write + link update (old prec)
    #pragma unroll
    for (int e=0;e<16;e++){
      int f = tid + 512*e;
      int m = f >> 7, w = f & 127;
      mem[m*MEMLD+w] = mem[m*MEMLD+w]*(1.0f - ww[m]*er[w]) + ww[m]*wv[w];
    }
    #pragma unroll
    for (int e=0;e<8;e++){
      int f = tid + 512*e;
      int i = f >> 6, j = f & 63;
      float lv = (1.0f - ww[i] - ww[j])*link[i*LNKLD+j] + ww[i]*prec[j];
      link[i*LNKLD+j] = (i==j) ? 0.0f : lv;
    }
    __syncthreads();

    // ---- Phase G: precedence update + post-write mem norms
    if (tid < M) prec[tid] = (1.0f - s_wwsum)*prec[tid] + ww[tid];
    {
      int row = tid >> 3, sub = tid & 7;
      float ss = 0.f;
      #pragma unroll
      for (int i=0;i<16;i++){ float v = mem[row*MEMLD + sub + 8*i]; ss += v*v; }
      ss += __shfl_down(ss,4,8); ss += __shfl_down(ss,2,8); ss += __shfl_down(ss,1,8);
      if (sub==0) memnorm[row] = 1.0f/(sqrtf(ss)+DELTA);
    }
    __syncthreads();

    // ---- Phase H+J (merged): read dots AND fwd/bwd via link (old rw)
    {
      int r = tid >> 7, m = (tid >> 1) & 63, sub = tid & 1;
      float d = 0.f;
      #pragma unroll 8
      for (int i=0;i<64;i++){ int e = sub + 2*i; d += mem[m*MEMLD + e]*rk[r*W + e]; }
      d += __shfl_down(d,1,2);
      if (sub==0) cwm[r*M+m] = d * memnorm[m] * s_rkinv[r] * rstr[r];
    }
    if (tid < 256){
      int r = tid >> 6, i = tid & 63;
      float a = 0.f;
      #pragma unroll 8
      for (int j=0;j<M;j++) a += link[i*LNKLD+j]*rw[r*M+j];
      fwd[r*M+i] = a;
    } else {
      int q = tid - 256;
      int r = q >> 6, j = q & 63;
      float a = 0.f;
      #pragma unroll 8
      for (int i=0;i<M;i++) a += rw[r*M+i]*link[i*LNKLD+j];
      bwd[r*M+j] = a;
    }
    __syncthreads();

    // ---- Phase I+K (merged): per-head softmax, rw updated in-register
    if (wave < RH){
      int r = wave;
      float x = cwm[r*M + lane];
      float mx = waveAllMax(x);
      float e = expf(x-mx);
      float s = waveAllSum(e);
      float c = e/s;
      rw[r*M+lane] = rmode[3*r]*bwd[r*M+lane] + rmode[3*r+1]*fwd[r*M+lane]
                   + rmode[3*r+2]*c;
    }
    __syncthreads();

    // ---- Phase L: read vectors -> stash (half 0 writes)
    {
      int r = tid >> 7, w = tid & 127;
      float a = 0.f;
      #pragma unroll 8
      for (int m=0;m<M;m++) a += rw[r*M+m]*mem[m*MEMLD+w];
      if (half == 0) stash[bt*640 + 128 + tid] = a;
    }
  }
}

extern "C" void kernel_launch(void* const* d_in, const int* in_sizes, int n_in,
                              void* d_out, int out_size, void* d_ws, size_t ws_size,
                              hipStream_t stream)
{
  const int*   tokens  = (const int*)d_in[0];
  const float* emb     = (const float*)d_in[1];
  const float* w_ih0   = (const float*)d_in[2];
  const float* w_hh0   = (const float*)d_in[3];
  const float* b_ih0   = (const float*)d_in[4];
  const float* b_hh0   = (const float*)d_in[5];
  const float* w_ih1   = (const float*)d_in[6];
  const float* w_hh1   = (const float*)d_in[7];
  const float* b_ih1   = (const float*)d_in[8];
  const float* b_hh1   = (const float*)d_in[9];
  const float* w_iface = (const float*)d_in[10];
  const float* b_iface = (const float*)d_in[11];
  const float* w_out   = (const float*)d_in[12];
  const float* b_out   = (const float*)d_in[13];
  const float* w_fc    = (const float*)d_in[14];
  const float* b_fc    = (const float*)d_in[15];
  const float* h0      = (const float*)d_in[16];
  float* out = (float*)d_out;
  float* ws  = (float*)d_ws;

  float* xw0     = ws;                   // 512*512    = 262144
  float* whh0T   = xw0     + 262144;     // 128*512    = 65536
  float* w1catT  = whh0T   + 65536;      // 256*512    = 131072
  float* wifaceT = w1catT  + 131072;     // 128*919    = 117632
  float* wih0T   = wifaceT + 117632;     // 128*512    = 65536 (temp for xw0)
  float* stash   = wih0T   + 65536;      // 16384*640  = 10485760
  float* xbuf    = stash   + 10485760;   // 2*65536 + 128*928 = 249856
  unsigned* flags = (unsigned*)(xbuf + 249856);  // 128*2*3 = 768 uints
  // total ~11.28M floats ≈ 45.1 MB (fits: ws_size ≥ 52.8 MB verified in R2)

  auto tp = [&](const float* in, float* o, int rows, int cols, int use){
    int total = rows*use;
    k_transpose<<<(total+255)/256, 256, 0, stream>>>(in, o, rows, cols, use);
  };
  tp(w_ih0,   wih0T,          512, 640, 128);
  tp(w_hh0,   whh0T,          512, 128, 128);
  tp(w_ih1,   w1catT,         512, 128, 128);
  tp(w_hh1,   w1catT+128*G4,  512, 128, 128);
  tp(w_iface, wifaceT,        919, 128, 128);
  k_xw0<<<VOCAB, 512, 0, stream>>>(emb, wih0T, b_ih0, b_hh0, xw0);
  hipMemsetAsync(flags, 0, 768*sizeof(unsigned), stream);
  k_dnc<<<2*B, 512, 0, stream>>>(tokens, xw0, whh0T, w1catT, b_ih1, b_hh1,
                                 wifaceT, b_iface, h0, stash, xbuf, flags);
  k_tail<<<(B*T)/32, 512, 0, stream>>>(stash, w_out, b_out, w_fc, b_fc, out);
}

// Round 13
// 3279.126 us; speedup vs baseline: 2.0912x; 1.7870x over previous
//
#include <hip/hip_runtime.h>
#include <math.h>

#define B 128
#define T 128
#define H 128
#define RH 4
#define M 64
#define W 128
#define VOCAB 512
#define IFACE 919
#define G4 512
#define DELTA 1e-6f
#define CLIPV 20.0f

#define MEMLD 132   // mem row stride (W=128 + 4)
#define LNKLD 67    // link row stride (M=64 + 3)
#define CH 8        // xi chunk: steps per W_iface stream
#define XILD 928    // xi_chunk row stride (16B aligned)

__device__ __forceinline__ float sigmoidf_(float x){ return 1.0f/(1.0f+expf(-x)); }
__device__ __forceinline__ float softplusf_(float x){
  return fmaxf(x, 0.0f) + log1pf(expf(-fabsf(x)));
}
__device__ __forceinline__ float waveAllSum(float v){
  for (int off=1; off<64; off<<=1) v += __shfl_xor(v, off, 64);
  return v;
}
__device__ __forceinline__ float waveAllMax(float v){
  for (int off=1; off<64; off<<=1) v = fmaxf(v, __shfl_xor(v, off, 64));
  return v;
}

__global__ void k_transpose(const float* __restrict__ in, float* __restrict__ out,
                            int rows, int cols, int use_cols){
  int idx = blockIdx.x*blockDim.x + threadIdx.x;
  int total = rows*use_cols;
  if (idx < total){
    int r = idx / use_cols, c = idx - r*use_cols;
    out[c*rows + r] = in[r*cols + c];
  }
}

// xw0[v][g] = emb[v]·w_ih0[g][0:128] + b_ih0[g] + b_hh0[g]  (coalesced via wih0T)
__global__ void k_xw0(const float* __restrict__ emb, const float* __restrict__ wih0T,
                      const float* __restrict__ b_ih0, const float* __restrict__ b_hh0,
                      float* __restrict__ xw0){
  __shared__ float e[H];
  int v = blockIdx.x, g = threadIdx.x;
  if (g < H) e[g] = emb[v*H + g];
  __syncthreads();
  float acc = b_ih0[g] + b_hh0[g];
  #pragma unroll 8
  for (int k=0;k<H;k++) acc += e[k]*wih0T[k*G4 + g];
  xw0[v*G4 + g] = acc;
}

// fused tail: per 32 (b,t) rows -> Y = stash·w_out^T + b_out -> logits -> out
__launch_bounds__(512, 1)
__global__ void k_tail(const float* __restrict__ stash, const float* __restrict__ w_out,
                       const float* __restrict__ b_out, const float* __restrict__ w_fc,
                       const float* __restrict__ b_fc, float* __restrict__ out){
  __shared__ __align__(16) float S[32*644];
  __shared__ float Y[32*129];
  const int tid = threadIdx.x;
  const long bt0 = (long)blockIdx.x*32;

  for (int idx = tid; idx < 32*640; idx += 512){
    int bt = idx / 640, k = idx - bt*640;
    S[bt*644 + k] = stash[(bt0+bt)*640 + k];
  }
  __syncthreads();
  { // Y[bt][o]
    int og = tid >> 5, bt = tid & 31;
    const float4* s4 = (const float4*)(S + bt*644);
    #pragma unroll
    for (int oo = 0; oo < 8; ++oo){
      int o = og*8 + oo;
      const float4* w4 = (const float4*)(w_out + (size_t)o*640);
      float acc = b_out[o];
      #pragma unroll 8
      for (int k4 = 0; k4 < 160; ++k4){
        float4 w = w4[k4], s = s4[k4];
        acc += w.x*s.x + w.y*s.y + w.z*s.z + w.w*s.w;
      }
      Y[bt*129 + o] = acc;
    }
  }
  __syncthreads();
  { // logits, coalesced on t
    int t = tid & 31, vg = tid >> 5;
    int b  = (int)(bt0 >> 7);
    int tb = (int)(bt0 & 127);
    const float* yr = Y + t*129;
    #pragma unroll 2
    for (int vv = 0; vv < 32; ++vv){
      int v = vg*32 + vv;
      const float4* w4 = (const float4*)(w_fc + (size_t)v*H);
      float acc = b_fc[v];
      #pragma unroll 8
      for (int k4 = 0; k4 < 32; ++k4){
        float4 w = w4[k4];
        int k = k4*4;
        acc += w.x*yr[k] + w.y*yr[k+1] + w.z*yr[k+2] + w.w*yr[k+3];
      }
      out[((size_t)b*VOCAB + v)*T + tb + t] = acc;
    }
  }
}

// two-phase DNC: phase 1 = pure LSTM scan (read-vecs never feed back — the
// reference concatenates ZEROS); phase 2 = chunked xi-GEMM (W_iface streamed
// once per CH steps) + weight-free DNC memory scan.
__launch_bounds__(512, 1)
__global__ void k_dnc2(const int* __restrict__ tokens,
                       const float* __restrict__ xw0,
                       const float* __restrict__ whh0T,
                       const float* __restrict__ w1catT,
                       const float* __restrict__ b_ih1,
                       const float* __restrict__ b_hh1,
                       const float* __restrict__ wifaceT,
                       const float* __restrict__ b_iface,
                       const float* __restrict__ h0,
                       float* __restrict__ outg,
                       float* __restrict__ stash)
{
  const int b = blockIdx.x;
  const int tid = threadIdx.x;
  const int lane = tid & 63;
  const int wave = tid >> 6;

  __shared__ __align__(16) float hcat[2*H];           // h0 || h1
  __shared__ __align__(16) float c0s[H], c1s[H];
  __shared__ __align__(16) float mem[M*MEMLD];
  __shared__ float link[M*LNKLD];
  __shared__ float prec[M], ww[M], usage[M];
  __shared__ float rw[RH*M];
  __shared__ __align__(16) float gates[G4];
  __shared__ __align__(16) float rk[RH*W];
  __shared__ float wk[W], er[W], wv[W];
  __shared__ float memnorm[M];
  __shared__ float wcw[M], alloc_s[M];
  __shared__ float cwm[RH*M], fwd[RH*M], bwd[RH*M];
  __shared__ int   tok[T];
  __shared__ float rstr[RH], rmode[RH*3];
  __shared__ float s_wstr, s_ag, s_wg, s_wwsum, s_wkinv, s_rkinv[RH];
  __shared__ __align__(16) float xi_chunk[CH*XILD];   // CH xi rows
  __shared__ __align__(16) float out_s[CH*H];         // CH out rows

  // loop-invariant hoists
  const float b1sum = b_ih1[tid] + b_hh1[tid];
  const bool  two = (tid < IFACE-512);
  const float bi0 = b_iface[tid];
  const float bi1 = two ? b_iface[tid+512] : 0.f;

  if (tid < H){
    float hv0 = h0[0*B*H + b*H + tid];
    float hv1 = h0[1*B*H + b*H + tid];
    hcat[tid]=hv0; hcat[H+tid]=hv1; c0s[tid]=hv0; c1s[tid]=hv1;
  }
  if (tid < T) tok[tid] = tokens[b*T + tid];
  __syncthreads();

  // ===================== PHASE 1: pure LSTM scan ===========================
  for (int t = 0; t < T; ++t){
    // mv0 (R7-proven pattern)
    {
      float acc = xw0[(size_t)tok[t]*G4 + tid];
      const float* wp = whh0T + tid;
      #pragma unroll 8
      for (int k=0;k<H;k++) acc += hcat[k]*wp[k*G4];
      gates[tid] = acc;
    }
    __syncthreads();
    if (tid < H){
      float ig = sigmoidf_(gates[tid]);
      float ff = sigmoidf_(gates[H+tid]);
      float gg = tanhf(gates[2*H+tid]);
      float og = sigmoidf_(gates[3*H+tid]);
      float c2 = ff*c0s[tid] + ig*gg;
      c0s[tid] = c2;
      hcat[tid] = og*tanhf(c2);
    }
    __syncthreads();
    // mv1 (R7-proven pattern, K=256)
    {
      float acc = b1sum;
      const float* wp1 = w1catT + tid;            // w_ih1
      const float* wp2 = w1catT + 128*G4 + tid;   // w_hh1
      #pragma unroll 4
      for (int k=0;k<H;k++) acc += hcat[k]*wp1[k*G4] + hcat[H+k]*wp2[k*G4];
      gates[tid] = acc;
    }
    __syncthreads();
    if (tid < H){
      float ig = sigmoidf_(gates[tid]);
      float ff = sigmoidf_(gates[H+tid]);
      float gg = tanhf(gates[2*H+tid]);
      float og = sigmoidf_(gates[3*H+tid]);
      float c2 = ff*c1s[tid] + ig*gg;
      c1s[tid] = c2;
      float h2 = og*tanhf(c2);
      hcat[H+tid] = h2;
      float ov = fminf(fmaxf(h2, -CLIPV), CLIPV);
      const long bt = (long)b*T + t;
      outg[bt*H + tid] = ov;          // for phase-2 xi GEMM
      stash[bt*640 + tid] = ov;       // for tail
    }
    __syncthreads();
  }

  // ===================== PHASE 2: chunked xi + DNC scan ====================
  for (int i = tid; i < M*MEMLD; i += 512) mem[i]=0.f;
  for (int i = tid; i < M*LNKLD; i += 512) link[i]=0.f;
  if (tid < M){ prec[tid]=0.f; ww[tid]=0.f; usage[tid]=0.f; }
  if (tid < RH*M) rw[tid]=0.f;
  __syncthreads();

  for (int c = 0; c < T/CH; ++c){
    // stage CH out rows (same-block producer; __syncthreads ordered)
    for (int idx = tid; idx < CH*H; idx += 512)
      out_s[idx] = outg[((size_t)b*T + c*CH)*H + idx];
    __syncthreads();

    // xi GEMM: each thread computes <=2 iface columns for all CH steps.
    // W_iface streamed ONCE per CH steps (8x amortization vs per-step).
    {
      float a0[CH], a1[CH];
      #pragma unroll
      for (int r=0;r<CH;r++){ a0[r] = bi0; a1[r] = bi1; }
      const float* wp1 = wifaceT + tid;
      const float* wp2 = wifaceT + tid + 512;
      #pragma unroll 4
      for (int k=0;k<H;k++){
        float w1 = wp1[k*IFACE];
        float w2 = two ? wp2[k*IFACE] : 0.f;
        #pragma unroll
        for (int r=0;r<CH;r++){
          float o = out_s[r*H + k];
          a0[r] += o*w1;
          a1[r] += o*w2;
        }
      }
      #pragma unroll
      for (int r=0;r<CH;r++){
        xi_chunk[r*XILD + tid] = a0[r];
        if (two) xi_chunk[r*XILD + tid + 512] = a1[r];
      }
    }
    __syncthreads();

    for (int s = 0; s < CH; ++s){
      const int t = c*CH + s;
      const long bt = (long)b*T + t;
      const float* xc = xi_chunk + s*XILD;

      // ---- parse + usage + key norms + pre-write mem-norm (merged)
      rk[tid] = tanhf(xc[tid]);
      if (tid < W){
        wk[tid] = tanhf(xc[516+tid]);
        er[tid] = sigmoidf_(xc[645+tid]);
        wv[tid] = tanhf(xc[773+tid]);
      }
      if (tid < RH){
        rstr[tid] = softplusf_(xc[512+tid]);
        float a0 = xc[907+3*tid], a1 = xc[908+3*tid], a2 = xc[909+3*tid];
        float mx = fmaxf(a0, fmaxf(a1,a2));
        float e0=expf(a0-mx), e1=expf(a1-mx), e2=expf(a2-mx);
        float s3 = e0+e1+e2;
        rmode[3*tid]=e0/s3; rmode[3*tid+1]=e1/s3; rmode[3*tid+2]=e2/s3;
      }
      if (tid == 0){
        s_wstr = softplusf_(xc[644]);
        s_ag = sigmoidf_(xc[905]);
        s_wg = sigmoidf_(xc[906]);
      }
      if (tid < M){   // usage update (prev ww, prev rw)
        float f0 = sigmoidf_(xc[901]);
        float f1 = sigmoidf_(xc[902]);
        float f2 = sigmoidf_(xc[903]);
        float f3 = sigmoidf_(xc[904]);
        float um = usage[tid] + (1.0f-usage[tid])*ww[tid];
        float psi = (1.0f - f0*rw[tid])      * (1.0f - f1*rw[M+tid])
                  * (1.0f - f2*rw[2*M+tid])  * (1.0f - f3*rw[3*M+tid]);
        usage[tid] = um*psi;
      }
      {
        int row = tid >> 3, sub = tid & 7;
        float ss = 0.f;
        #pragma unroll
        for (int i=0;i<16;i++){ float v = mem[row*MEMLD + sub + 8*i]; ss += v*v; }
        ss += __shfl_down(ss,4,8); ss += __shfl_down(ss,2,8); ss += __shfl_down(ss,1,8);
        if (sub==0) memnorm[row] = 1.0f/(sqrtf(ss)+DELTA);
      }
      if (wave == 0){      // write-key norm (tanh recomputed from xi)
        float v0 = tanhf(xc[516+lane]), v1 = tanhf(xc[516+lane+64]);
        float ss = waveAllSum(v0*v0+v1*v1);
        if (lane==0) s_wkinv = 1.0f/(sqrtf(ss)+DELTA);
      } else if (wave <= RH){   // read-key norms
        int r = wave-1;
        float v0 = tanhf(xc[r*W+lane]), v1 = tanhf(xc[r*W+lane+64]);
        float ss = waveAllSum(v0*v0+v1*v1);
        if (lane==0) s_rkinv[r] = 1.0f/(sqrtf(ss)+DELTA);
      }
      __syncthreads();

      // ---- Phase C: write content scores (pre-write memory)
      {
        int m = tid >> 3, sub = tid & 7;
        float d = 0.f;
        #pragma unroll
        for (int i=0;i<16;i++){ int e = sub + 8*i; d += mem[m*MEMLD + e]*wk[e]; }
        d += __shfl_down(d,4,8); d += __shfl_down(d,2,8); d += __shfl_down(d,1,8);
        if (sub==0) wcw[m] = d * memnorm[m] * s_wkinv * s_wstr;
      }
      __syncthreads();

      // ---- Phase D: wave0 softmax(wcw); wave1 allocation via bitonic argsort
      if (wave == 0){
        float x = wcw[lane];
        float mx = waveAllMax(x);
        float e = expf(x-mx);
        float s2 = waveAllSum(e);
        wcw[lane] = e/s2;
      } else if (wave == 1){
        float u = DELTA + (1.0f-DELTA)*usage[lane];
        int idx = lane;
        for (int k=2;k<=64;k<<=1){
          for (int j=k>>1;j>0;j>>=1){
            float ou = __shfl_xor(u, j, 64);
            int   oi = __shfl_xor(idx, j, 64);
            bool up = ((lane & k) == 0);
            bool iLower = ((lane & j) == 0);
            bool otherLess = (ou < u) || (ou == u && oi < idx);
            bool takeOther = (up == iLower) ? otherLess : !otherLess;
            if (takeOther){ u = ou; idx = oi; }
          }
        }
        float p = u;
        for (int d=1; d<64; d<<=1){
          float pv = __shfl_up(p, d, 64);
          if (lane >= d) p *= pv;
        }
        float ep = __shfl_up(p, 1, 64);
        if (lane == 0) ep = 1.0f;
        alloc_s[idx] = (1.0f - u) * ep;
      }
      __syncthreads();

      // ---- Phase E: write weights + sum
      if (tid < M){
        float wwm = s_wg*(s_ag*alloc_s[tid] + (1.0f-s_ag)*wcw[tid]);
        ww[tid] = wwm;
        float s2 = waveAllSum(wwm);
        if (lane==0) s_wwsum = s2;
      }
      __syncthreads();

      // ---- Phase F: memory write + link update (old prec)
      #pragma unroll
      for (int e=0;e<16;e++){
        int f = tid + 512*e;
        int m = f >> 7, w = f & 127;
        mem[m*MEMLD+w] = mem[m*MEMLD+w]*(1.0f - ww[m]*er[w]) + ww[m]*wv[w];
      }
      #pragma unroll
      for (int e=0;e<8;e++){
        int f = tid + 512*e;
        int i = f >> 6, j = f & 63;
        float lv = (1.0f - ww[i] - ww[j])*link[i*LNKLD+j] + ww[i]*prec[j];
        link[i*LNKLD+j] = (i==j) ? 0.0f : lv;
      }
      __syncthreads();

      // ---- Phase G: precedence update + post-write mem norms
      if (tid < M) prec[tid] = (1.0f - s_wwsum)*prec[tid] + ww[tid];
      {
        int row = tid >> 3, sub = tid & 7;
        float ss = 0.f;
        #pragma unroll
        for (int i=0;i<16;i++){ float v = mem[row*MEMLD + sub + 8*i]; ss += v*v; }
        ss += __shfl_down(ss,4,8); ss += __shfl_down(ss,2,8); ss += __shfl_down(ss,1,8);
        if (sub==0) memnorm[row] = 1.0f/(sqrtf(ss)+DELTA);
      }
      __syncthreads();

      // ---- Phase H+J (merged): read dots AND fwd/bwd via link (old rw)
      {
        int r = tid >> 7, m = (tid >> 1) & 63, sub = tid & 1;
        float d = 0.f;
        #pragma unroll 8
        for (int i=0;i<64;i++){ int e = sub + 2*i; d += mem[m*MEMLD + e]*rk[r*W + e]; }
        d += __shfl_down(d,1,2);
        if (sub==0) cwm[r*M+m] = d * memnorm[m] * s_rkinv[r] * rstr[r];
      }
      if (tid < 256){
        int r = tid >> 6, i = tid & 63;
        float a = 0.f;
        #pragma unroll 8
        for (int j=0;j<M;j++) a += link[i*LNKLD+j]*rw[r*M+j];
        fwd[r*M+i] = a;
      } else {
        int q = tid - 256;
        int r = q >> 6, j = q & 63;
        float a = 0.f;
        #pragma unroll 8
        for (int i=0;i<M;i++) a += rw[r*M+i]*link[i*LNKLD+j];
        bwd[r*M+j] = a;
      }
      __syncthreads();

      // ---- Phase I+K (merged): per-head softmax, rw updated in-register
      if (wave < RH){
        int r = wave;
        float x = cwm[r*M + lane];
        float mx = waveAllMax(x);
        float e = expf(x-mx);
        float s2 = waveAllSum(e);
        float cc = e/s2;
        rw[r*M+lane] = rmode[3*r]*bwd[r*M+lane] + rmode[3*r+1]*fwd[r*M+lane]
                     + rmode[3*r+2]*cc;
      }
      __syncthreads();

      // ---- Phase L: read vectors -> stash (no trailing barrier needed)
      {
        int r = tid >> 7, w = tid & 127;
        float a = 0.f;
        #pragma unroll 8
        for (int m=0;m<M;m++) a += rw[r*M+m]*mem[m*MEMLD+w];
        stash[bt*640 + 128 + tid] = a;
      }
      __syncthreads();
    }
  }
}

extern "C" void kernel_launch(void* const* d_in, const int* in_sizes, int n_in,
                              void* d_out, int out_size, void* d_ws, size_t ws_size,
                              hipStream_t stream)
{
  const int*   tokens  = (const int*)d_in[0];
  const float* emb     = (const float*)d_in[1];
  const float* w_ih0   = (const float*)d_in[2];
  const float* w_hh0   = (const float*)d_in[3];
  const float* b_ih0   = (const float*)d_in[4];
  const float* b_hh0   = (const float*)d_in[5];
  const float* w_ih1   = (const float*)d_in[6];
  const float* w_hh1   = (const float*)d_in[7];
  const float* b_ih1   = (const float*)d_in[8];
  const float* b_hh1   = (const float*)d_in[9];
  const float* w_iface = (const float*)d_in[10];
  const float* b_iface = (const float*)d_in[11];
  const float* w_out   = (const float*)d_in[12];
  const float* b_out   = (const float*)d_in[13];
  const float* w_fc    = (const float*)d_in[14];
  const float* b_fc    = (const float*)d_in[15];
  const float* h0      = (const float*)d_in[16];
  float* out = (float*)d_out;
  float* ws  = (float*)d_ws;

  float* xw0     = ws;                   // 262144
  float* whh0T   = xw0     + 262144;     // 65536
  float* w1catT  = whh0T   + 65536;      // 131072
  float* wifaceT = w1catT  + 131072;     // 117632
  float* wih0T   = wifaceT + 117632;     // 65536 (temp for xw0)
  float* stash   = wih0T   + 65536;      // 10485760
  float* outg    = stash   + 10485760;   // 16384*128 = 2097152
  // total 13,224,832 floats = 52.90 MB  (< 53.05 MB bound proven in R2)

  auto tp = [&](const float* in, float* o, int rows, int cols, int use){
    int total = rows*use;
    k_transpose<<<(total+255)/256, 256, 0, stream>>>(in, o, rows, cols, use);
  };
  tp(w_ih0,   wih0T,          512, 640, 128);
  tp(w_hh0,   whh0T,          512, 128, 128);
  tp(w_ih1,   w1catT,         512, 128, 128);
  tp(w_hh1,   w1catT+128*G4,  512, 128, 128);
  tp(w_iface, wifaceT,        919, 128, 128);
  k_xw0<<<VOCAB, 512, 0, stream>>>(emb, wih0T, b_ih0, b_hh0, xw0);
  k_dnc2<<<B, 512, 0, stream>>>(tokens, xw0, whh0T, w1catT, b_ih1, b_hh1,
                                wifaceT, b_iface, h0, outg, stash);
  k_tail<<<(B*T)/32, 512, 0, stream>>>(stash, w_out, b_out, w_fc, b_fc, out);
}

// Round 14
// 2500.590 us; speedup vs baseline: 2.7423x; 1.3113x over previous
//
#include <hip/hip_runtime.h>
#include <math.h>

#define B 128
#define T 128
#define H 128
#define RH 4
#define M 64
#define W 128
#define VOCAB 512
#define IFACE 919
#define G4 512
#define DELTA 1e-6f
#define CLIPV 20.0f

#define MEMLD 132   // mem row stride (W=128 + 4)
#define LNKLD 67    // link row stride (M=64 + 3)
#define CH 8        // xi chunk: steps per W_iface stream / pipeline grain
#define XILD 928    // xi_chunk row stride (16B aligned)

__device__ __forceinline__ float sigmoidf_(float x){ return 1.0f/(1.0f+expf(-x)); }
__device__ __forceinline__ float softplusf_(float x){
  return fmaxf(x, 0.0f) + log1pf(expf(-fabsf(x)));
}
__device__ __forceinline__ float waveAllSum(float v){
  for (int off=1; off<64; off<<=1) v += __shfl_xor(v, off, 64);
  return v;
}
__device__ __forceinline__ float waveAllMax(float v){
  for (int off=1; off<64; off<<=1) v = fmaxf(v, __shfl_xor(v, off, 64));
  return v;
}

__global__ void k_transpose(const float* __restrict__ in, float* __restrict__ out,
                            int rows, int cols, int use_cols){
  int idx = blockIdx.x*blockDim.x + threadIdx.x;
  int total = rows*use_cols;
  if (idx < total){
    int r = idx / use_cols, c = idx - r*use_cols;
    out[c*rows + r] = in[r*cols + c];
  }
}

// xw0[v][g] = emb[v]·w_ih0[g][0:128] + b_ih0[g] + b_hh0[g]  (coalesced via wih0T)
__global__ void k_xw0(const float* __restrict__ emb, const float* __restrict__ wih0T,
                      const float* __restrict__ b_ih0, const float* __restrict__ b_hh0,
                      float* __restrict__ xw0){
  __shared__ float e[H];
  int v = blockIdx.x, g = threadIdx.x;
  if (g < H) e[g] = emb[v*H + g];
  __syncthreads();
  float acc = b_ih0[g] + b_hh0[g];
  #pragma unroll 8
  for (int k=0;k<H;k++) acc += e[k]*wih0T[k*G4 + g];
  xw0[v*G4 + g] = acc;
}

// fused tail: per 32 (b,t) rows -> Y = stash·w_out^T + b_out -> logits -> out
__launch_bounds__(512, 1)
__global__ void k_tail(const float* __restrict__ stash, const float* __restrict__ w_out,
                       const float* __restrict__ b_out, const float* __restrict__ w_fc,
                       const float* __restrict__ b_fc, float* __restrict__ out){
  __shared__ __align__(16) float S[32*644];
  __shared__ float Y[32*129];
  const int tid = threadIdx.x;
  const long bt0 = (long)blockIdx.x*32;

  for (int idx = tid; idx < 32*640; idx += 512){
    int bt = idx / 640, k = idx - bt*640;
    S[bt*644 + k] = stash[(bt0+bt)*640 + k];
  }
  __syncthreads();
  { // Y[bt][o]
    int og = tid >> 5, bt = tid & 31;
    const float4* s4 = (const float4*)(S + bt*644);
    #pragma unroll
    for (int oo = 0; oo < 8; ++oo){
      int o = og*8 + oo;
      const float4* w4 = (const float4*)(w_out + (size_t)o*640);
      float acc = b_out[o];
      #pragma unroll 8
      for (int k4 = 0; k4 < 160; ++k4){
        float4 w = w4[k4], s = s4[k4];
        acc += w.x*s.x + w.y*s.y + w.z*s.z + w.w*s.w;
      }
      Y[bt*129 + o] = acc;
    }
  }
  __syncthreads();
  { // logits, coalesced on t
    int t = tid & 31, vg = tid >> 5;
    int b  = (int)(bt0 >> 7);
    int tb = (int)(bt0 & 127);
    const float* yr = Y + t*129;
    #pragma unroll 2
    for (int vv = 0; vv < 32; ++vv){
      int v = vg*32 + vv;
      const float4* w4 = (const float4*)(w_fc + (size_t)v*H);
      float acc = b_fc[v];
      #pragma unroll 8
      for (int k4 = 0; k4 < 32; ++k4){
        float4 w = w4[k4];
        int k = k4*4;
        acc += w.x*yr[k] + w.y*yr[k+1] + w.z*yr[k+2] + w.w*yr[k+3];
      }
      out[((size_t)b*VOCAB + v)*T + tb + t] = acc;
    }
  }
}

// Producer/consumer pipeline: blocks 0..127 = LSTM scan (weight-streaming),
// blocks 128..255 = DNC memory scan (weight-free). Producer b publishes a
// flag per CH-step chunk; consumer b waits. Pair (b, b+128) lands on the
// SAME XCD ((b+128)%8==b%8) -> handshake stays in coherent same-XCD L2.
__launch_bounds__(512, 1)
__global__ void k_dnc(const int* __restrict__ tokens,
                      const float* __restrict__ xw0,
                      const float* __restrict__ whh0T,
                      const float* __restrict__ w1catT,
                      const float* __restrict__ b_ih1,
                      const float* __restrict__ b_hh1,
                      const float* __restrict__ wifaceT,
                      const float* __restrict__ b_iface,
                      const float* __restrict__ h0,
                      float* __restrict__ outg,
                      float* __restrict__ stash,
                      unsigned* __restrict__ flags)
{
  const int role = blockIdx.x >> 7;   // 0 = producer (LSTM), 1 = consumer (DNC)
  const int b = blockIdx.x & 127;
  const int tid = threadIdx.x;
  const int lane = tid & 63;
  const int wave = tid >> 6;

  __shared__ __align__(16) float hcat[2*H];
  __shared__ __align__(16) float c0s[H], c1s[H];
  __shared__ __align__(16) float mem[M*MEMLD];
  __shared__ float link[M*LNKLD];
  __shared__ float prec[M], ww[M], usage[M];
  __shared__ float rw[RH*M];
  __shared__ __align__(16) float gates[G4];
  __shared__ __align__(16) float rk[RH*W];
  __shared__ float wk[W], er[W], wv[W];
  __shared__ float memnorm[M];
  __shared__ float wcw[M], alloc_s[M];
  __shared__ float cwm[RH*M], fwd[RH*M], bwd[RH*M];
  __shared__ int   tok[T];
  __shared__ float rstr[RH], rmode[RH*3];
  __shared__ float s_wstr, s_ag, s_wg, s_wwsum, s_wkinv, s_rkinv[RH];
  __shared__ __align__(16) float xi_chunk[CH*XILD];
  __shared__ __align__(16) float out_s[CH*H];

  if (role == 0){
    // =================== PRODUCER: pure LSTM scan =========================
    const float b1sum = b_ih1[tid] + b_hh1[tid];
    if (tid < H){
      float hv0 = h0[0*B*H + b*H + tid];
      float hv1 = h0[1*B*H + b*H + tid];
      hcat[tid]=hv0; hcat[H+tid]=hv1; c0s[tid]=hv0; c1s[tid]=hv1;
    }
    if (tid < T) tok[tid] = tokens[b*T + tid];
    __syncthreads();

    for (int t = 0; t < T; ++t){
      // mv0 (R7-proven pattern)
      {
        float acc = xw0[(size_t)tok[t]*G4 + tid];
        const float* wp = whh0T + tid;
        #pragma unroll 8
        for (int k=0;k<H;k++) acc += hcat[k]*wp[k*G4];
        gates[tid] = acc;
      }
      __syncthreads();
      if (tid < H){
        float ig = sigmoidf_(gates[tid]);
        float ff = sigmoidf_(gates[H+tid]);
        float gg = tanhf(gates[2*H+tid]);
        float og = sigmoidf_(gates[3*H+tid]);
        float c2 = ff*c0s[tid] + ig*gg;
        c0s[tid] = c2;
        hcat[tid] = og*tanhf(c2);
      }
      __syncthreads();
      // mv1 (R7-proven pattern, K=256)
      {
        float acc = b1sum;
        const float* wp1 = w1catT + tid;
        const float* wp2 = w1catT + 128*G4 + tid;
        #pragma unroll 4
        for (int k=0;k<H;k++) acc += hcat[k]*wp1[k*G4] + hcat[H+k]*wp2[k*G4];
        gates[tid] = acc;
      }
      __syncthreads();
      if (tid < H){
        float ig = sigmoidf_(gates[tid]);
        float ff = sigmoidf_(gates[H+tid]);
        float gg = tanhf(gates[2*H+tid]);
        float og = sigmoidf_(gates[3*H+tid]);
        float c2 = ff*c1s[tid] + ig*gg;
        c1s[tid] = c2;
        float h2 = og*tanhf(c2);
        hcat[H+tid] = h2;
        float ov = fminf(fmaxf(h2, -CLIPV), CLIPV);
        const long bt = (long)b*T + t;
        outg[bt*H + tid] = ov;
        stash[bt*640 + tid] = ov;
      }
      __syncthreads();
      if ((t & (CH-1)) == CH-1){
        // all outg stores for this chunk issued & drained (barrier above)
        if (tid == 0)
          __hip_atomic_store(&flags[b], (unsigned)((t>>3)+1),
                             __ATOMIC_RELEASE, __HIP_MEMORY_SCOPE_AGENT);
      }
    }
  } else {
    // =================== CONSUMER: chunked xi + DNC scan ===================
    const bool  two = (tid < IFACE-512);
    const float bi0 = b_iface[tid];
    const float bi1 = two ? b_iface[tid+512] : 0.f;

    for (int i = tid; i < M*MEMLD; i += 512) mem[i]=0.f;
    for (int i = tid; i < M*LNKLD; i += 512) link[i]=0.f;
    if (tid < M){ prec[tid]=0.f; ww[tid]=0.f; usage[tid]=0.f; }
    if (tid < RH*M) rw[tid]=0.f;
    __syncthreads();

    for (int c = 0; c < T/CH; ++c){
      // wait for producer chunk c (same-XCD L2 handshake)
      if (tid == 0){
        while (__hip_atomic_load(&flags[b], __ATOMIC_ACQUIRE,
                                 __HIP_MEMORY_SCOPE_AGENT) < (unsigned)(c+1))
          __builtin_amdgcn_s_sleep(4);
      }
      __syncthreads();

      // stage CH out rows
      for (int idx = tid; idx < CH*H; idx += 512)
        out_s[idx] = outg[((size_t)b*T + c*CH)*H + idx];
      __syncthreads();

      // xi GEMM: W_iface streamed once per CH steps
      {
        float a0[CH], a1[CH];
        #pragma unroll
        for (int r=0;r<CH;r++){ a0[r] = bi0; a1[r] = bi1; }
        const float* wp1 = wifaceT + tid;
        const float* wp2 = wifaceT + tid + 512;
        #pragma unroll 4
        for (int k=0;k<H;k++){
          float w1 = wp1[k*IFACE];
          float w2 = two ? wp2[k*IFACE] : 0.f;
          #pragma unroll
          for (int r=0;r<CH;r++){
            float o = out_s[r*H + k];
            a0[r] += o*w1;
            a1[r] += o*w2;
          }
        }
        #pragma unroll
        for (int r=0;r<CH;r++){
          xi_chunk[r*XILD + tid] = a0[r];
          if (two) xi_chunk[r*XILD + tid + 512] = a1[r];
        }
      }
      __syncthreads();

      for (int s = 0; s < CH; ++s){
        const int t = c*CH + s;
        const long bt = (long)b*T + t;
        const float* xc = xi_chunk + s*XILD;

        // ---- parse + usage + key norms + pre-write mem-norm (merged)
        rk[tid] = tanhf(xc[tid]);
        if (tid < W){
          wk[tid] = tanhf(xc[516+tid]);
          er[tid] = sigmoidf_(xc[645+tid]);
          wv[tid] = tanhf(xc[773+tid]);
        }
        if (tid < RH){
          rstr[tid] = softplusf_(xc[512+tid]);
          float a0 = xc[907+3*tid], a1 = xc[908+3*tid], a2 = xc[909+3*tid];
          float mx = fmaxf(a0, fmaxf(a1,a2));
          float e0=expf(a0-mx), e1=expf(a1-mx), e2=expf(a2-mx);
          float s3 = e0+e1+e2;
          rmode[3*tid]=e0/s3; rmode[3*tid+1]=e1/s3; rmode[3*tid+2]=e2/s3;
        }
        if (tid == 0){
          s_wstr = softplusf_(xc[644]);
          s_ag = sigmoidf_(xc[905]);
          s_wg = sigmoidf_(xc[906]);
        }
        if (tid < M){
          float f0 = sigmoidf_(xc[901]);
          float f1 = sigmoidf_(xc[902]);
          float f2 = sigmoidf_(xc[903]);
          float f3 = sigmoidf_(xc[904]);
          float um = usage[tid] + (1.0f-usage[tid])*ww[tid];
          float psi = (1.0f - f0*rw[tid])      * (1.0f - f1*rw[M+tid])
                    * (1.0f - f2*rw[2*M+tid])  * (1.0f - f3*rw[3*M+tid]);
          usage[tid] = um*psi;
        }
        {
          int row = tid >> 3, sub = tid & 7;
          float ss = 0.f;
          #pragma unroll
          for (int i=0;i<16;i++){ float v = mem[row*MEMLD + sub + 8*i]; ss += v*v; }
          ss += __shfl_down(ss,4,8); ss += __shfl_down(ss,2,8); ss += __shfl_down(ss,1,8);
          if (sub==0) memnorm[row] = 1.0f/(sqrtf(ss)+DELTA);
        }
        if (wave == 0){
          float v0 = tanhf(xc[516+lane]), v1 = tanhf(xc[516+lane+64]);
          float ss = waveAllSum(v0*v0+v1*v1);
          if (lane==0) s_wkinv = 1.0f/(sqrtf(ss)+DELTA);
        } else if (wave <= RH){
          int r = wave-1;
          float v0 = tanhf(xc[r*W+lane]), v1 = tanhf(xc[r*W+lane+64]);
          float ss = waveAllSum(v0*v0+v1*v1);
          if (lane==0) s_rkinv[r] = 1.0f/(sqrtf(ss)+DELTA);
        }
        __syncthreads();

        // ---- Phase C: write content scores (pre-write memory)
        {
          int m = tid >> 3, sub = tid & 7;
          float d = 0.f;
          #pragma unroll
          for (int i=0;i<16;i++){ int e = sub + 8*i; d += mem[m*MEMLD + e]*wk[e]; }
          d += __shfl_down(d,4,8); d += __shfl_down(d,2,8); d += __shfl_down(d,1,8);
          if (sub==0) wcw[m] = d * memnorm[m] * s_wkinv * s_wstr;
        }
        __syncthreads();

        // ---- Phase D: wave0 softmax(wcw); wave1 allocation sort
        if (wave == 0){
          float x = wcw[lane];
          float mx = waveAllMax(x);
          float e = expf(x-mx);
          float s2 = waveAllSum(e);
          wcw[lane] = e/s2;
        } else if (wave == 1){
          float u = DELTA + (1.0f-DELTA)*usage[lane];
          int idx = lane;
          for (int k=2;k<=64;k<<=1){
            for (int j=k>>1;j>0;j>>=1){
              float ou = __shfl_xor(u, j, 64);
              int   oi = __shfl_xor(idx, j, 64);
              bool up = ((lane & k) == 0);
              bool iLower = ((lane & j) == 0);
              bool otherLess = (ou < u) || (ou == u && oi < idx);
              bool takeOther = (up == iLower) ? otherLess : !otherLess;
              if (takeOther){ u = ou; idx = oi; }
            }
          }
          float p = u;
          for (int d=1; d<64; d<<=1){
            float pv = __shfl_up(p, d, 64);
            if (lane >= d) p *= pv;
          }
          float ep = __shfl_up(p, 1, 64);
          if (lane == 0) ep = 1.0f;
          alloc_s[idx] = (1.0f - u) * ep;
        }
        __syncthreads();

        // ---- Phase E: write weights + sum
        if (tid < M){
          float wwm = s_wg*(s_ag*alloc_s[tid] + (1.0f-s_ag)*wcw[tid]);
          ww[tid] = wwm;
          float s2 = waveAllSum(wwm);
          if (lane==0) s_wwsum = s2;
        }
        __syncthreads();

        // ---- Phase F: memory write + link update (old prec)
        #pragma unroll
        for (int e=0;e<16;e++){
          int f = tid + 512*e;
          int m = f >> 7, w = f & 127;
          mem[m*MEMLD+w] = mem[m*MEMLD+w]*(1.0f - ww[m]*er[w]) + ww[m]*wv[w];
        }
        #pragma unroll
        for (int e=0;e<8;e++){
          int f = tid + 512*e;
          int i = f >> 6, j = f & 63;
          float lv = (1.0f - ww[i] - ww[j])*link[i*LNKLD+j] + ww[i]*prec[j];
          link[i*LNKLD+j] = (i==j) ? 0.0f : lv;
        }
        __syncthreads();

        // ---- Phase G: precedence update + post-write mem norms
        if (tid < M) prec[tid] = (1.0f - s_wwsum)*prec[tid] + ww[tid];
        {
          int row = tid >> 3, sub = tid & 7;
          float ss = 0.f;
          #pragma unroll
          for (int i=0;i<16;i++){ float v = mem[row*MEMLD + sub + 8*i]; ss += v*v; }
          ss += __shfl_down(ss,4,8); ss += __shfl_down(ss,2,8); ss += __shfl_down(ss,1,8);
          if (sub==0) memnorm[row] = 1.0f/(sqrtf(ss)+DELTA);
        }
        __syncthreads();

        // ---- Phase H+J (merged): read dots AND fwd/bwd via link (old rw)
        {
          int r = tid >> 7, m = (tid >> 1) & 63, sub = tid & 1;
          float d = 0.f;
          #pragma unroll 8
          for (int i=0;i<64;i++){ int e = sub + 2*i; d += mem[m*MEMLD + e]*rk[r*W + e]; }
          d += __shfl_down(d,1,2);
          if (sub==0) cwm[r*M+m] = d * memnorm[m] * s_rkinv[r] * rstr[r];
        }
        if (tid < 256){
          int r = tid >> 6, i = tid & 63;
          float a = 0.f;
          #pragma unroll 8
          for (int j=0;j<M;j++) a += link[i*LNKLD+j]*rw[r*M+j];
          fwd[r*M+i] = a;
        } else {
          int q = tid - 256;
          int r = q >> 6, j = q & 63;
          float a = 0.f;
          #pragma unroll 8
          for (int i=0;i<M;i++) a += rw[r*M+i]*link[i*LNKLD+j];
          bwd[r*M+j] = a;
        }
        __syncthreads();

        // ---- Phase I+K (merged): per-head softmax, rw updated in-register
        if (wave < RH){
          int r = wave;
          float x = cwm[r*M + lane];
          float mx = waveAllMax(x);
          float e = expf(x-mx);
          float s2 = waveAllSum(e);
          float cc = e/s2;
          rw[r*M+lane] = rmode[3*r]*bwd[r*M+lane] + rmode[3*r+1]*fwd[r*M+lane]
                       + rmode[3*r+2]*cc;
        }
        __syncthreads();

        // ---- Phase L: read vectors -> stash
        {
          int r = tid >> 7, w = tid & 127;
          float a = 0.f;
          #pragma unroll 8
          for (int m=0;m<M;m++) a += rw[r*M+m]*mem[m*MEMLD+w];
          stash[bt*640 + 128 + tid] = a;
        }
        __syncthreads();
      }
    }
  }
}

extern "C" void kernel_launch(void* const* d_in, const int* in_sizes, int n_in,
                              void* d_out, int out_size, void* d_ws, size_t ws_size,
                              hipStream_t stream)
{
  const int*   tokens  = (const int*)d_in[0];
  const float* emb     = (const float*)d_in[1];
  const float* w_ih0   = (const float*)d_in[2];
  const float* w_hh0   = (const float*)d_in[3];
  const float* b_ih0   = (const float*)d_in[4];
  const float* b_hh0   = (const float*)d_in[5];
  const float* w_ih1   = (const float*)d_in[6];
  const float* w_hh1   = (const float*)d_in[7];
  const float* b_ih1   = (const float*)d_in[8];
  const float* b_hh1   = (const float*)d_in[9];
  const float* w_iface = (const float*)d_in[10];
  const float* b_iface = (const float*)d_in[11];
  const float* w_out   = (const float*)d_in[12];
  const float* b_out   = (const float*)d_in[13];
  const float* w_fc    = (const float*)d_in[14];
  const float* b_fc    = (const float*)d_in[15];
  const float* h0      = (const float*)d_in[16];
  float* out = (float*)d_out;
  float* ws  = (float*)d_ws;

  float* xw0     = ws;                   // 262144
  float* whh0T   = xw0     + 262144;     // 65536
  float* w1catT  = whh0T   + 65536;      // 131072
  float* wifaceT = w1catT  + 131072;     // 117632
  float* wih0T   = wifaceT + 117632;     // 65536 (temp for xw0)
  float* stash   = wih0T   + 65536;      // 10485760
  float* outg    = stash   + 10485760;   // 2097152
  unsigned* flags = (unsigned*)(outg + 2097152);   // 128 uints
  // total 52.90 MB + 512 B (< 53.05 MB bound proven in R2)

  auto tp = [&](const float* in, float* o, int rows, int cols, int use){
    int total = rows*use;
    k_transpose<<<(total+255)/256, 256, 0, stream>>>(in, o, rows, cols, use);
  };
  tp(w_ih0,   wih0T,          512, 640, 128);
  tp(w_hh0,   whh0T,          512, 128, 128);
  tp(w_ih1,   w1catT,         512, 128, 128);
  tp(w_hh1,   w1catT+128*G4,  512, 128, 128);
  tp(w_iface, wifaceT,        919, 128, 128);
  k_xw0<<<VOCAB, 512, 0, stream>>>(emb, wih0T, b_ih0, b_hh0, xw0);
  hipMemsetAsync(flags, 0, 128*sizeof(unsigned), stream);
  k_dnc<<<2*B, 512, 0, stream>>>(tokens, xw0, whh0T, w1catT, b_ih1, b_hh1,
                                 wifaceT, b_iface, h0, outg, stash, flags);
  k_tail<<<(B*T)/32, 512, 0, stream>>>(stash, w_out, b_out, w_fc, b_fc, out);
}

// Round 15
// 2369.321 us; speedup vs baseline: 2.8942x; 1.0554x over previous
//
#include <hip/hip_runtime.h>
#include <math.h>

#define B 128
#define T 128
#define H 128
#define RH 4
#define M 64
#define W 128
#define VOCAB 512
#define IFACE 919
#define G4 512
#define DELTA 1e-6f
#define CLIPV 20.0f

#define MEMLD 133   // mem row stride; 133%32=5 coprime -> Phase H conflict-free
#define LNKLD 67    // link row stride (67%32=3, coprime)
#define CH 8        // pipeline grain: steps per chunk
#define XILD 928    // xi row stride (16B aligned)

__device__ __forceinline__ float sigmoidf_(float x){ return 1.0f/(1.0f+expf(-x)); }
__device__ __forceinline__ float softplusf_(float x){
  return fmaxf(x, 0.0f) + log1pf(expf(-fabsf(x)));
}
__device__ __forceinline__ float waveAllSum(float v){
  for (int off=1; off<64; off<<=1) v += __shfl_xor(v, off, 64);
  return v;
}
__device__ __forceinline__ float waveAllMax(float v){
  for (int off=1; off<64; off<<=1) v = fmaxf(v, __shfl_xor(v, off, 64));
  return v;
}

__global__ void k_transpose(const float* __restrict__ in, float* __restrict__ out,
                            int rows, int cols, int use_cols){
  int idx = blockIdx.x*blockDim.x + threadIdx.x;
  int total = rows*use_cols;
  if (idx < total){
    int r = idx / use_cols, c = idx - r*use_cols;
    out[c*rows + r] = in[r*cols + c];
  }
}

// xw0[v][g] = emb[v]·w_ih0[g][0:128] + b_ih0[g] + b_hh0[g]  (coalesced via wih0T)
__global__ void k_xw0(const float* __restrict__ emb, const float* __restrict__ wih0T,
                      const float* __restrict__ b_ih0, const float* __restrict__ b_hh0,
                      float* __restrict__ xw0){
  __shared__ float e[H];
  int v = blockIdx.x, g = threadIdx.x;
  if (g < H) e[g] = emb[v*H + g];
  __syncthreads();
  float acc = b_ih0[g] + b_hh0[g];
  #pragma unroll 8
  for (int k=0;k<H;k++) acc += e[k]*wih0T[k*G4 + g];
  xw0[v*G4 + g] = acc;
}

// fused tail: per 32 (b,t) rows -> Y = stash·w_out^T + b_out -> logits -> out
__launch_bounds__(512, 1)
__global__ void k_tail(const float* __restrict__ stash, const float* __restrict__ w_out,
                       const float* __restrict__ b_out, const float* __restrict__ w_fc,
                       const float* __restrict__ b_fc, float* __restrict__ out){
  __shared__ __align__(16) float S[32*644];
  __shared__ float Y[32*129];
  const int tid = threadIdx.x;
  const long bt0 = (long)blockIdx.x*32;

  for (int idx = tid; idx < 32*640; idx += 512){
    int bt = idx / 640, k = idx - bt*640;
    S[bt*644 + k] = stash[(bt0+bt)*640 + k];
  }
  __syncthreads();
  { // Y[bt][o]
    int og = tid >> 5, bt = tid & 31;
    const float4* s4 = (const float4*)(S + bt*644);
    #pragma unroll
    for (int oo = 0; oo < 8; ++oo){
      int o = og*8 + oo;
      const float4* w4 = (const float4*)(w_out + (size_t)o*640);
      float acc = b_out[o];
      #pragma unroll 8
      for (int k4 = 0; k4 < 160; ++k4){
        float4 w = w4[k4], s = s4[k4];
        acc += w.x*s.x + w.y*s.y + w.z*s.z + w.w*s.w;
      }
      Y[bt*129 + o] = acc;
    }
  }
  __syncthreads();
  { // logits, coalesced on t
    int t = tid & 31, vg = tid >> 5;
    int b  = (int)(bt0 >> 7);
    int tb = (int)(bt0 & 127);
    const float* yr = Y + t*129;
    #pragma unroll 2
    for (int vv = 0; vv < 32; ++vv){
      int v = vg*32 + vv;
      const float4* w4 = (const float4*)(w_fc + (size_t)v*H);
      float acc = b_fc[v];
      #pragma unroll 8
      for (int k4 = 0; k4 < 32; ++k4){
        float4 w = w4[k4];
        int k = k4*4;
        acc += w.x*yr[k] + w.y*yr[k+1] + w.z*yr[k+2] + w.w*yr[k+3];
      }
      out[((size_t)b*VOCAB + v)*T + tb + t] = acc;
    }
  }
}

// Producer/consumer pipeline. Producer (blocks 0..127): LSTM scan + per-chunk
// xi GEMM (fills its L2-stall windows), publishes xi into a 2-slot ring.
// Consumer (blocks 128..255): weight-free DNC memory scan from staged xi.
__launch_bounds__(512, 1)
__global__ void k_dnc(const int* __restrict__ tokens,
                      const float* __restrict__ xw0,
                      const float* __restrict__ whh0T,
                      const float* __restrict__ w1catT,
                      const float* __restrict__ b_ih1,
                      const float* __restrict__ b_hh1,
                      const float* __restrict__ wifaceT,
                      const float* __restrict__ b_iface,
                      const float* __restrict__ h0,
                      float* __restrict__ xibuf,
                      float* __restrict__ stash,
                      unsigned* __restrict__ pflag,
                      unsigned* __restrict__ cflag)
{
  const int role = blockIdx.x >> 7;   // 0 = producer (LSTM+xi), 1 = consumer (DNC)
  const int b = blockIdx.x & 127;
  const int tid = threadIdx.x;
  const int lane = tid & 63;
  const int wave = tid >> 6;

  __shared__ __align__(16) float hcat[2*H];
  __shared__ __align__(16) float c0s[H], c1s[H];
  __shared__ __align__(16) float mem[M*MEMLD];
  __shared__ float link[M*LNKLD];
  __shared__ float prec[M], ww[M], usage[M];
  __shared__ float rw[RH*M];
  __shared__ __align__(16) float gates[G4];
  __shared__ __align__(16) float rk[RH*W];
  __shared__ float wk[W], er[W], wv[W];
  __shared__ float memnorm[M];
  __shared__ float wcw[M], alloc_s[M];
  __shared__ float cwm[RH*M], fwd[RH*M], bwd[RH*M];
  __shared__ int   tok[T];
  __shared__ float rstr[RH], rmode[RH*3];
  __shared__ float s_wstr, s_ag, s_wg, s_wwsum, s_wkinv, s_rkinv[RH];
  __shared__ __align__(16) float xi_chunk[CH*XILD];
  __shared__ __align__(16) float out_s[CH*H];

  if (role == 0){
    // =================== PRODUCER: LSTM scan + chunk xi GEMM ================
    const float b1sum = b_ih1[tid] + b_hh1[tid];
    const bool  two = (tid < IFACE-512);
    const float bi0 = b_iface[tid];
    const float bi1 = two ? b_iface[tid+512] : 0.f;

    if (tid < H){
      float hv0 = h0[0*B*H + b*H + tid];
      float hv1 = h0[1*B*H + b*H + tid];
      hcat[tid]=hv0; hcat[H+tid]=hv1; c0s[tid]=hv0; c1s[tid]=hv1;
    }
    if (tid < T) tok[tid] = tokens[b*T + tid];
    __syncthreads();

    for (int c = 0; c < T/CH; ++c){
      for (int s = 0; s < CH; ++s){
        const int t = c*CH + s;
        // mv0 (R7-proven pattern)
        {
          float acc = xw0[(size_t)tok[t]*G4 + tid];
          const float* wp = whh0T + tid;
          #pragma unroll 8
          for (int k=0;k<H;k++) acc += hcat[k]*wp[k*G4];
          gates[tid] = acc;
        }
        __syncthreads();
        if (tid < H){
          float ig = sigmoidf_(gates[tid]);
          float ff = sigmoidf_(gates[H+tid]);
          float gg = tanhf(gates[2*H+tid]);
          float og = sigmoidf_(gates[3*H+tid]);
          float c2 = ff*c0s[tid] + ig*gg;
          c0s[tid] = c2;
          hcat[tid] = og*tanhf(c2);
        }
        __syncthreads();
        // mv1 (R7-proven pattern, K=256)
        {
          float acc = b1sum;
          const float* wp1 = w1catT + tid;
          const float* wp2 = w1catT + 128*G4 + tid;
          #pragma unroll 4
          for (int k=0;k<H;k++) acc += hcat[k]*wp1[k*G4] + hcat[H+k]*wp2[k*G4];
          gates[tid] = acc;
        }
        __syncthreads();
        if (tid < H){
          float ig = sigmoidf_(gates[tid]);
          float ff = sigmoidf_(gates[H+tid]);
          float gg = tanhf(gates[2*H+tid]);
          float og = sigmoidf_(gates[3*H+tid]);
          float c2 = ff*c1s[tid] + ig*gg;
          c1s[tid] = c2;
          float h2 = og*tanhf(c2);
          hcat[H+tid] = h2;
          float ov = fminf(fmaxf(h2, -CLIPV), CLIPV);
          out_s[s*H + tid] = ov;               // for this chunk's xi GEMM
          stash[((long)b*T + t)*640 + tid] = ov;
        }
        __syncthreads();
      }

      // backpressure: before overwriting slot c&1, consumer must have staged c-2
      if (c >= 2){
        if (tid == 0){
          while (__hip_atomic_load(&cflag[b], __ATOMIC_ACQUIRE,
                                   __HIP_MEMORY_SCOPE_AGENT) < (unsigned)(c-1))
            __builtin_amdgcn_s_sleep(2);
        }
        __syncthreads();
      }

      // xi GEMM for this chunk (W_iface streamed once per CH steps)
      {
        float* xslot = xibuf + ((size_t)b*2 + (c&1))*(CH*XILD);
        float a0[CH], a1[CH];
        #pragma unroll
        for (int r=0;r<CH;r++){ a0[r] = bi0; a1[r] = bi1; }
        const float* wp1 = wifaceT + tid;
        const float* wp2 = wifaceT + tid + 512;
        #pragma unroll 4
        for (int k=0;k<H;k++){
          float w1 = wp1[k*IFACE];
          float w2 = two ? wp2[k*IFACE] : 0.f;
          #pragma unroll
          for (int r=0;r<CH;r++){
            float o = out_s[r*H + k];
            a0[r] += o*w1;
            a1[r] += o*w2;
          }
        }
        #pragma unroll
        for (int r=0;r<CH;r++){
          xslot[r*XILD + tid] = a0[r];
          if (two) xslot[r*XILD + tid + 512] = a1[r];
        }
      }
      __syncthreads();   // all xi stores issued
      if (tid == 0)
        __hip_atomic_store(&pflag[b], (unsigned)(c+1),
                           __ATOMIC_RELEASE, __HIP_MEMORY_SCOPE_AGENT);
    }
  } else {
    // =================== CONSUMER: weight-free DNC scan =====================
    for (int i = tid; i < M*MEMLD; i += 512) mem[i]=0.f;
    for (int i = tid; i < M*LNKLD; i += 512) link[i]=0.f;
    if (tid < M){ prec[tid]=0.f; ww[tid]=0.f; usage[tid]=0.f; }
    if (tid < RH*M) rw[tid]=0.f;
    __syncthreads();

    for (int c = 0; c < T/CH; ++c){
      // wait for producer chunk c (same-XCD L2 handshake)
      if (tid == 0){
        while (__hip_atomic_load(&pflag[b], __ATOMIC_ACQUIRE,
                                 __HIP_MEMORY_SCOPE_AGENT) < (unsigned)(c+1))
          __builtin_amdgcn_s_sleep(4);
      }
      __syncthreads();

      // stage xi chunk (30KB, float4-coalesced), then free the slot
      {
        const float4* src = (const float4*)(xibuf + ((size_t)b*2 + (c&1))*(CH*XILD));
        float4* dst = (float4*)xi_chunk;
        for (int i = tid; i < CH*XILD/4; i += 512) dst[i] = src[i];
      }
      __syncthreads();
      if (tid == 0)
        __hip_atomic_store(&cflag[b], (unsigned)(c+1),
                           __ATOMIC_RELEASE, __HIP_MEMORY_SCOPE_AGENT);

      for (int s = 0; s < CH; ++s){
        const int t = c*CH + s;
        const long bt = (long)b*T + t;
        const float* xc = xi_chunk + s*XILD;

        // ---- parse + usage + key norms + pre-write mem-norm (merged)
        rk[tid] = tanhf(xc[tid]);
        if (tid < W){
          wk[tid] = tanhf(xc[516+tid]);
          er[tid] = sigmoidf_(xc[645+tid]);
          wv[tid] = tanhf(xc[773+tid]);
        }
        if (tid < RH){
          rstr[tid] = softplusf_(xc[512+tid]);
          float a0 = xc[907+3*tid], a1 = xc[908+3*tid], a2 = xc[909+3*tid];
          float mx = fmaxf(a0, fmaxf(a1,a2));
          float e0=expf(a0-mx), e1=expf(a1-mx), e2=expf(a2-mx);
          float s3 = e0+e1+e2;
          rmode[3*tid]=e0/s3; rmode[3*tid+1]=e1/s3; rmode[3*tid+2]=e2/s3;
        }
        if (tid == 0){
          s_wstr = softplusf_(xc[644]);
          s_ag = sigmoidf_(xc[905]);
          s_wg = sigmoidf_(xc[906]);
        }
        if (tid < M){
          float f0 = sigmoidf_(xc[901]);
          float f1 = sigmoidf_(xc[902]);
          float f2 = sigmoidf_(xc[903]);
          float f3 = sigmoidf_(xc[904]);
          float um = usage[tid] + (1.0f-usage[tid])*ww[tid];
          float psi = (1.0f - f0*rw[tid])      * (1.0f - f1*rw[M+tid])
                    * (1.0f - f2*rw[2*M+tid])  * (1.0f - f3*rw[3*M+tid]);
          usage[tid] = um*psi;
        }
        {
          int row = tid >> 3, sub = tid & 7;
          float ss = 0.f;
          #pragma unroll
          for (int i=0;i<16;i++){ float v = mem[row*MEMLD + sub + 8*i]; ss += v*v; }
          ss += __shfl_down(ss,4,8); ss += __shfl_down(ss,2,8); ss += __shfl_down(ss,1,8);
          if (sub==0) memnorm[row] = 1.0f/(sqrtf(ss)+DELTA);
        }
        if (wave == 0){
          float v0 = tanhf(xc[516+lane]), v1 = tanhf(xc[516+lane+64]);
          float ss = waveAllSum(v0*v0+v1*v1);
          if (lane==0) s_wkinv = 1.0f/(sqrtf(ss)+DELTA);
        } else if (wave <= RH){
          int r = wave-1;
          float v0 = tanhf(xc[r*W+lane]), v1 = tanhf(xc[r*W+lane+64]);
          float ss = waveAllSum(v0*v0+v1*v1);
          if (lane==0) s_rkinv[r] = 1.0f/(sqrtf(ss)+DELTA);
        }
        __syncthreads();

        // ---- Phase C: write content scores (pre-write memory)
        {
          int m = tid >> 3, sub = tid & 7;
          float d = 0.f;
          #pragma unroll
          for (int i=0;i<16;i++){ int e = sub + 8*i; d += mem[m*MEMLD + e]*wk[e]; }
          d += __shfl_down(d,4,8); d += __shfl_down(d,2,8); d += __shfl_down(d,1,8);
          if (sub==0) wcw[m] = d * memnorm[m] * s_wkinv * s_wstr;
        }
        __syncthreads();

        // ---- Phase D: wave0 softmax(wcw); wave1 allocation sort
        if (wave == 0){
          float x = wcw[lane];
          float mx = waveAllMax(x);
          float e = expf(x-mx);
          float s2 = waveAllSum(e);
          wcw[lane] = e/s2;
        } else if (wave == 1){
          float u = DELTA + (1.0f-DELTA)*usage[lane];
          int idx = lane;
          for (int k=2;k<=64;k<<=1){
            for (int j=k>>1;j>0;j>>=1){
              float ou = __shfl_xor(u, j, 64);
              int   oi = __shfl_xor(idx, j, 64);
              bool up = ((lane & k) == 0);
              bool iLower = ((lane & j) == 0);
              bool otherLess = (ou < u) || (ou == u && oi < idx);
              bool takeOther = (up == iLower) ? otherLess : !otherLess;
              if (takeOther){ u = ou; idx = oi; }
            }
          }
          float p = u;
          for (int d=1; d<64; d<<=1){
            float pv = __shfl_up(p, d, 64);
            if (lane >= d) p *= pv;
          }
          float ep = __shfl_up(p, 1, 64);
          if (lane == 0) ep = 1.0f;
          alloc_s[idx] = (1.0f - u) * ep;
        }
        __syncthreads();

        // ---- Phase F (E folded): mem write + link update, ww on the fly
        {
          const float cg = s_wg, ag = s_ag;
          #pragma unroll
          for (int e=0;e<16;e++){
            int f = tid + 512*e;
            int m = f >> 7, w = f & 127;
            float wwm = cg*(ag*alloc_s[m] + (1.0f-ag)*wcw[m]);
            mem[m*MEMLD+w] = mem[m*MEMLD+w]*(1.0f - wwm*er[w]) + wwm*wv[w];
          }
          #pragma unroll
          for (int e=0;e<8;e++){
            int f = tid + 512*e;
            int i = f >> 6, j = f & 63;
            float wwi = cg*(ag*alloc_s[i] + (1.0f-ag)*wcw[i]);
            float wwj = cg*(ag*alloc_s[j] + (1.0f-ag)*wcw[j]);
            float lv = (1.0f - wwi - wwj)*link[i*LNKLD+j] + wwi*prec[j];
            link[i*LNKLD+j] = (i==j) ? 0.0f : lv;
          }
          if (tid < M) ww[tid] = cg*(ag*alloc_s[tid] + (1.0f-ag)*wcw[tid]);
        }
        __syncthreads();

        // ---- Phase G: post-write mem norms
        {
          int row = tid >> 3, sub = tid & 7;
          float ss = 0.f;
          #pragma unroll
          for (int i=0;i<16;i++){ float v = mem[row*MEMLD + sub + 8*i]; ss += v*v; }
          ss += __shfl_down(ss,4,8); ss += __shfl_down(ss,2,8); ss += __shfl_down(ss,1,8);
          if (sub==0) memnorm[row] = 1.0f/(sqrtf(ss)+DELTA);
        }
        __syncthreads();

        // ---- Phase H+J: read dots AND fwd/bwd via link (old rw); wwsum@wave7
        {
          int r = tid >> 7, m = (tid >> 1) & 63, sub = tid & 1;
          float d = 0.f;
          #pragma unroll 8
          for (int i=0;i<64;i++){ int e = sub + 2*i; d += mem[m*MEMLD + e]*rk[r*W + e]; }
          d += __shfl_down(d,1,2);
          if (sub==0) cwm[r*M+m] = d * memnorm[m] * s_rkinv[r] * rstr[r];
        }
        if (tid < 256){
          int r = tid >> 6, i = tid & 63;
          float a = 0.f;
          #pragma unroll 8
          for (int j=0;j<M;j++) a += link[i*LNKLD+j]*rw[r*M+j];
          fwd[r*M+i] = a;
        } else {
          int q = tid - 256;
          int r = q >> 6, j = q & 63;
          float a = 0.f;
          #pragma unroll 8
          for (int i=0;i<M;i++) a += rw[r*M+i]*link[i*LNKLD+j];
          bwd[r*M+j] = a;
        }
        if (wave == 7){
          float s2 = waveAllSum(ww[lane]);
          if (lane==0) s_wwsum = s2;
        }
        __syncthreads();

        // ---- Phase I+K: per-head softmax + rw update; prec@wave4
        if (wave < RH){
          int r = wave;
          float x = cwm[r*M + lane];
          float mx = waveAllMax(x);
          float e = expf(x-mx);
          float s2 = waveAllSum(e);
          float cc = e/s2;
          rw[r*M+lane] = rmode[3*r]*bwd[r*M+lane] + rmode[3*r+1]*fwd[r*M+lane]
                       + rmode[3*r+2]*cc;
        } else if (wave == 4){
          prec[lane] = (1.0f - s_wwsum)*prec[lane] + ww[lane];
        }
        __syncthreads();

        // ---- Phase L: read vectors -> stash
        {
          int r = tid >> 7, w = tid & 127;
          float a = 0.f;
          #pragma unroll 8
          for (int m=0;m<M;m++) a += rw[r*M+m]*mem[m*MEMLD+w];
          stash[bt*640 + 128 + tid] = a;
        }
        __syncthreads();
      }
    }
  }
}

extern "C" void kernel_launch(void* const* d_in, const int* in_sizes, int n_in,
                              void* d_out, int out_size, void* d_ws, size_t ws_size,
                              hipStream_t stream)
{
  const int*   tokens  = (const int*)d_in[0];
  const float* emb     = (const float*)d_in[1];
  const float* w_ih0   = (const float*)d_in[2];
  const float* w_hh0   = (const float*)d_in[3];
  const float* b_ih0   = (const float*)d_in[4];
  const float* b_hh0   = (const float*)d_in[5];
  const float* w_ih1   = (const float*)d_in[6];
  const float* w_hh1   = (const float*)d_in[7];
  const float* b_ih1   = (const float*)d_in[8];
  const float* b_hh1   = (const float*)d_in[9];
  const float* w_iface = (const float*)d_in[10];
  const float* b_iface = (const float*)d_in[11];
  const float* w_out   = (const float*)d_in[12];
  const float* b_out   = (const float*)d_in[13];
  const float* w_fc    = (const float*)d_in[14];
  const float* b_fc    = (const float*)d_in[15];
  const float* h0      = (const float*)d_in[16];
  float* out = (float*)d_out;
  float* ws  = (float*)d_ws;

  float* xw0     = ws;                   // 262144
  float* whh0T   = xw0     + 262144;     // 65536
  float* w1catT  = whh0T   + 65536;      // 131072
  float* wifaceT = w1catT  + 131072;     // 117632
  float* wih0T   = wifaceT + 117632;     // 65536 (temp for xw0)
  float* stash   = wih0T   + 65536;      // 10485760
  float* xibuf   = stash   + 10485760;   // 128*2*7424 = 1900544
  unsigned* pflag = (unsigned*)(xibuf + 1900544);   // 128
  unsigned* cflag = pflag + 128;                    // 128
  // total 13,028,224 floats + 1KB = 52.11 MB (< 53.05 MB bound proven in R2)

  auto tp = [&](const float* in, float* o, int rows, int cols, int use){
    int total = rows*use;
    k_transpose<<<(total+255)/256, 256, 0, stream>>>(in, o, rows, cols, use);
  };
  tp(w_ih0,   wih0T,          512, 640, 128);
  tp(w_hh0,   whh0T,          512, 128, 128);
  tp(w_ih1,   w1catT,         512, 128, 128);
  tp(w_hh1,   w1catT+128*G4,  512, 128, 128);
  tp(w_iface, wifaceT,        919, 128, 128);
  k_xw0<<<VOCAB, 512, 0, stream>>>(emb, wih0T, b_ih0, b_hh0, xw0);
  hipMemsetAsync(pflag, 0, 256*sizeof(unsigned), stream);
  k_dnc<<<2*B, 512, 0, stream>>>(tokens, xw0, whh0T, w1catT, b_ih1, b_hh1,
                                 wifaceT, b_iface, h0, xibuf, stash,
                                 pflag, cflag);
  k_tail<<<(B*T)/32, 512, 0, stream>>>(stash, w_out, b_out, w_fc, b_fc, out);
}